// Round 1
// baseline (671.655 us; speedup 1.0000x reference)
//
#include <hip/hip_runtime.h>
#include <cstddef>

#define B_SZ    8
#define L_SEQ   2048
#define D_MODEL 1024
#define N_ST    64
#define N_REC   8
#define LC      256   // L_SEQ / N_REC

// klin[b][h][l] = sum_d u[b][l][d] * W[h][d] + bias[h]
// 64x64 output tile per block, K-tile 16, 256 threads, 4x4 micro-tile/thread.
__global__ __launch_bounds__(256) void gemm_klin(
    const float* __restrict__ u, const float* __restrict__ W,
    const float* __restrict__ bias, float* __restrict__ klin)
{
    __shared__ float Wt[16][68];  // [kd][h]  (68: 16B-aligned rows, 2-way banks only)
    __shared__ float Ut[16][68];  // [kd][l]
    const int b  = blockIdx.z;
    const int h0 = blockIdx.y << 6;
    const int l0 = blockIdx.x << 6;
    const int t  = threadIdx.x;
    const int tx = t & 15, ty = t >> 4;
    const int row = t >> 2, v = t & 3;

    const float* Wp = W + (size_t)(h0 + row) * D_MODEL + (v << 2);
    const float* Up = u + ((size_t)b * L_SEQ + l0 + row) * D_MODEL + (v << 2);

    float acc[4][4] = {};
    for (int kt = 0; kt < D_MODEL / 16; ++kt) {
        float4 wv = *(const float4*)(Wp + kt * 16);
        float4 uv = *(const float4*)(Up + kt * 16);
        __syncthreads();  // previous tile fully consumed
        Wt[(v<<2)+0][row] = wv.x; Wt[(v<<2)+1][row] = wv.y;
        Wt[(v<<2)+2][row] = wv.z; Wt[(v<<2)+3][row] = wv.w;
        Ut[(v<<2)+0][row] = uv.x; Ut[(v<<2)+1][row] = uv.y;
        Ut[(v<<2)+2][row] = uv.z; Ut[(v<<2)+3][row] = uv.w;
        __syncthreads();
        #pragma unroll
        for (int kd = 0; kd < 16; ++kd) {
            float4 av = *(const float4*)&Wt[kd][ty << 2];
            float4 bv = *(const float4*)&Ut[kd][tx << 2];
            float aa[4] = {av.x, av.y, av.z, av.w};
            float bb[4] = {bv.x, bv.y, bv.z, bv.w};
            #pragma unroll
            for (int i = 0; i < 4; ++i)
                #pragma unroll
                for (int j = 0; j < 4; ++j)
                    acc[i][j] = fmaf(aa[i], bb[j], acc[i][j]);
        }
    }
    const int hh = h0 + (ty << 2);
    const int ll = l0 + (tx << 2);
    #pragma unroll
    for (int i = 0; i < 4; ++i) {
        float bi = bias[hh + i];
        float4 o = { acc[i][0] + bi, acc[i][1] + bi, acc[i][2] + bi, acc[i][3] + bi };
        *(float4*)&klin[((size_t)b * D_MODEL + hh + i) * L_SEQ + ll] = o;
    }
}

// One block per (h, b): 64 threads (one per state n).
// 1) stage klin row in LDS (64 leading zeros for causal FIR)
// 2) compute 64 shift-kernel taps F[m] = sum_j C[j+m]*B[j] (+D at m=0)
// 3) FIR: kk[l] = sum_m F[m]*klin[l-m]
// 4) per-lane complex Horner s <- s*w + kk[l]; emit Re(dB*s) every 256 steps
__global__ __launch_bounds__(64) void expand(
    const float* __restrict__ klin,
    const float* __restrict__ shift_B, const float* __restrict__ shift_C,
    const float* __restrict__ ssm_k_D,
    const float* __restrict__ log_dt, const float* __restrict__ log_A_real,
    const float* __restrict__ A_imag, const float* __restrict__ B_re,
    const float* __restrict__ B_im, float* __restrict__ out)
{
    __shared__ float kl[64 + L_SEQ];
    __shared__ float kk[L_SEQ];
    __shared__ float Bs[64], Cs[64], Fs[64];
    const int h = blockIdx.x;
    const int b = blockIdx.y;
    const int n = threadIdx.x;

    Bs[n] = shift_B[h * 64 + n];
    Cs[n] = shift_C[h * 64 + n];
    kl[n] = 0.f;
    const float* krow = klin + ((size_t)b * D_MODEL + h) * L_SEQ;
    #pragma unroll
    for (int j = 0; j < L_SEQ / 64; ++j)
        kl[64 + n + j * 64] = krow[n + j * 64];
    __syncthreads();

    float f = (n == 0) ? ssm_k_D[h] : 0.f;
    for (int j = 0; j + n < 64; ++j)
        f = fmaf(Cs[j + n], Bs[j], f);
    Fs[n] = f;
    __syncthreads();

    for (int j = 0; j < L_SEQ / 64; ++j) {
        const int l = n + j * 64;
        float s = 0.f;
        #pragma unroll
        for (int m = 0; m < 64; ++m)
            s = fmaf(Fs[m], kl[64 + l - m], s);
        kk[l] = s;
    }
    __syncthreads();

    // per-state discretization
    const float dt   = expf(log_dt[h]);
    const float A_re = -expf(log_A_real[h * 64 + n]);
    const float A_im = A_imag[h * 64 + n];
    const float lr = dt * A_re, li = dt * A_im;
    const float er = expf(lr);
    const float w_re = er * cosf(li);
    const float w_im = er * sinf(li);
    const float den  = A_re * A_re + A_im * A_im;
    const float wm1r = w_re - 1.f, wm1i = w_im;
    const float tr = (wm1r * A_re + wm1i * A_im) / den;
    const float ti = (wm1i * A_re - wm1r * A_im) / den;
    const float br = B_re[h * 64 + n], bi = B_im[h * 64 + n];
    const float dB_re = br * tr - bi * ti;
    const float dB_im = br * ti + bi * tr;

    float s_re = 0.f, s_im = 0.f;
    for (int r = 0; r < N_REC; ++r) {
        const float* kc = &kk[r * LC];
        #pragma unroll 8
        for (int i = 0; i < LC; ++i) {
            const float vv = kc[i];
            const float nr = fmaf(s_re, w_re, fmaf(-s_im, w_im, vv));
            const float ni = fmaf(s_re, w_im, s_im * w_re);
            s_re = nr; s_im = ni;
        }
        out[(((size_t)b * N_REC + r) * D_MODEL + h) * 64 + n] =
            dB_re * s_re - dB_im * s_im;
    }
}

extern "C" void kernel_launch(void* const* d_in, const int* in_sizes, int n_in,
                              void* d_out, int out_size, void* d_ws, size_t ws_size,
                              hipStream_t stream)
{
    const float* u        = (const float*)d_in[0];
    const float* W        = (const float*)d_in[1];
    const float* bias     = (const float*)d_in[2];
    const float* shift_B  = (const float*)d_in[3];
    const float* shift_C  = (const float*)d_in[4];
    const float* ssm_k_D  = (const float*)d_in[5];
    const float* log_dt   = (const float*)d_in[6];
    const float* log_Ar   = (const float*)d_in[7];
    const float* A_imag   = (const float*)d_in[8];
    const float* B_re     = (const float*)d_in[9];
    const float* B_im     = (const float*)d_in[10];
    float* out  = (float*)d_out;
    float* klin = (float*)d_ws;  // 8*1024*2048*4 = 64 MB

    dim3 g1(L_SEQ / 64, D_MODEL / 64, B_SZ);
    gemm_klin<<<g1, 256, 0, stream>>>(u, W, bias, klin);

    dim3 g2(D_MODEL, B_SZ);
    expand<<<g2, 64, 0, stream>>>(klin, shift_B, shift_C, ssm_k_D, log_dt,
                                  log_Ar, A_imag, B_re, B_im, out);
}

// Round 2
// 205.434 us; speedup vs baseline: 3.2694x; 3.2694x over previous
//
#include <hip/hip_runtime.h>
#include <cstddef>
#include <cstdint>

#define L_SEQ 2048
#define DM    1024
#define NREC  8
#define BM 128
#define BN 128
#define BK 32
#define NT (DM / BK)

typedef __attribute__((ext_vector_type(8))) short short8;
typedef __attribute__((ext_vector_type(4))) float f32x4;

__device__ inline unsigned short f2bf(float f) {
    unsigned u = __float_as_uint(f);
    unsigned r = (u + 0x7FFFu + ((u >> 16) & 1u)) >> 16;
    return (unsigned short)r;
}
__device__ inline float bf2f(unsigned short s) {
    return __uint_as_float(((unsigned)s) << 16);
}
__device__ inline void gload_lds16(const void* g, void* l) {
    __builtin_amdgcn_global_load_lds(
        (const __attribute__((address_space(1))) void*)g,
        (__attribute__((address_space(3))) void*)l, 16, 0, 0);
}

// ---------------- u f32 -> bf16 ----------------
__global__ __launch_bounds__(256) void cvt_bf16(
    const float* __restrict__ in, unsigned short* __restrict__ out, int n)
{
    int i = (blockIdx.x * 256 + threadIdx.x) * 8;
    if (i >= n) return;
    f32x4 v0 = *(const f32x4*)(in + i);
    f32x4 v1 = *(const f32x4*)(in + i + 4);
    short8 o;
    o[0] = (short)f2bf(v0[0]); o[1] = (short)f2bf(v0[1]);
    o[2] = (short)f2bf(v0[2]); o[3] = (short)f2bf(v0[3]);
    o[4] = (short)f2bf(v1[0]); o[5] = (short)f2bf(v1[1]);
    o[6] = (short)f2bf(v1[2]); o[7] = (short)f2bf(v1[3]);
    *(short8*)(out + i) = o;
}

// ---------------- bf16 MFMA GEMM: klin[b][h][l] = sum_d W[h][d] u[b][l][d] + bias[h]
__global__ __launch_bounds__(256, 2) void gemm_klin(
    const float* __restrict__ W, const unsigned short* __restrict__ ub,
    const float* __restrict__ bias, unsigned short* __restrict__ klin)
{
    __shared__ unsigned short As[2][BM * BK];
    __shared__ unsigned short Bs[2][BM * BK];
    const int b  = blockIdx.z;
    const int h0 = blockIdx.y * BM;
    const int l0 = blockIdx.x * BN;
    const int tid = threadIdx.x;
    const int lane = tid & 63, wv = tid >> 6;

    // staging geometry: chunk c = 2*wv (+1); row = c*16 + lane/4; phys slot = lane&3
    const int r0 = wv * 32 + (lane >> 2);
    const int r1 = r0 + 16;
    const int sw0 = (r0 ^ (r0 >> 2)) & 3;
    const int sw1 = (r1 ^ (r1 >> 2)) & 3;
    const int col0 = (((lane & 3) ^ sw0) << 3);   // source-swizzled k offset
    const int col1 = (((lane & 3) ^ sw1) << 3);

    const unsigned short* gB0 = ub + ((size_t)(b * L_SEQ + l0 + r0)) * DM + col0;
    const unsigned short* gB1 = ub + ((size_t)(b * L_SEQ + l0 + r1)) * DM + col1;
    const float* gA0 = W + (size_t)(h0 + r0) * DM + col0;
    const float* gA1 = W + (size_t)(h0 + r1) * DM + col1;

    const int wm = wv >> 1, wn = wv & 1;
    const int lr = lane & 15, lk = lane >> 4;

    f32x4 acc[4][4];
    #pragma unroll
    for (int m = 0; m < 4; ++m)
        #pragma unroll
        for (int n = 0; n < 4; ++n) acc[m][n] = (f32x4){0.f, 0.f, 0.f, 0.f};

    // prologue: stage tile 0 completely
    gload_lds16(gB0, &Bs[0][(2 * wv) * 512]);
    gload_lds16(gB1, &Bs[0][(2 * wv + 1) * 512]);
    {
        f32x4 a0 = *(const f32x4*)(gA0);
        f32x4 a1 = *(const f32x4*)(gA0 + 4);
        f32x4 a2 = *(const f32x4*)(gA1);
        f32x4 a3 = *(const f32x4*)(gA1 + 4);
        short8 c0, c1;
        c0[0]=(short)f2bf(a0[0]); c0[1]=(short)f2bf(a0[1]); c0[2]=(short)f2bf(a0[2]); c0[3]=(short)f2bf(a0[3]);
        c0[4]=(short)f2bf(a1[0]); c0[5]=(short)f2bf(a1[1]); c0[6]=(short)f2bf(a1[2]); c0[7]=(short)f2bf(a1[3]);
        c1[0]=(short)f2bf(a2[0]); c1[1]=(short)f2bf(a2[1]); c1[2]=(short)f2bf(a2[2]); c1[3]=(short)f2bf(a2[3]);
        c1[4]=(short)f2bf(a3[0]); c1[5]=(short)f2bf(a3[1]); c1[6]=(short)f2bf(a3[2]); c1[7]=(short)f2bf(a3[3]);
        *(short8*)&As[0][r0 * 32 + (lane & 3) * 8] = c0;
        *(short8*)&As[0][r1 * 32 + (lane & 3) * 8] = c1;
    }

    for (int kt = 0; kt < NT; ++kt) {
        __syncthreads();   // buf[kt&1] staged (sync drains vmcnt+lgkmcnt)
        const int bf = kt & 1;
        f32x4 a0, a1, a2, a3;
        const bool more = (kt + 1 < NT);
        if (more) {
            const int ko = (kt + 1) * BK;
            gload_lds16(gB0 + ko, &Bs[bf ^ 1][(2 * wv) * 512]);
            gload_lds16(gB1 + ko, &Bs[bf ^ 1][(2 * wv + 1) * 512]);
            a0 = *(const f32x4*)(gA0 + ko);
            a1 = *(const f32x4*)(gA0 + ko + 4);
            a2 = *(const f32x4*)(gA1 + ko);
            a3 = *(const f32x4*)(gA1 + ko + 4);
        }
        // fragments (swizzled read)
        short8 af[4], bfr[4];
        #pragma unroll
        for (int m = 0; m < 4; ++m) {
            int row = wm * 64 + m * 16 + lr;
            int phys = lk ^ ((row ^ (row >> 2)) & 3);
            af[m] = *(const short8*)&As[bf][row * 32 + phys * 8];
        }
        #pragma unroll
        for (int n = 0; n < 4; ++n) {
            int row = wn * 64 + n * 16 + lr;
            int phys = lk ^ ((row ^ (row >> 2)) & 3);
            bfr[n] = *(const short8*)&Bs[bf][row * 32 + phys * 8];
        }
        #pragma unroll
        for (int m = 0; m < 4; ++m)
            #pragma unroll
            for (int n = 0; n < 4; ++n)
                acc[m][n] = __builtin_amdgcn_mfma_f32_16x16x32_bf16(af[m], bfr[n], acc[m][n], 0, 0, 0);
        if (more) {   // convert+write AFTER MFMAs: A-load latency hidden under compute
            short8 c0, c1;
            c0[0]=(short)f2bf(a0[0]); c0[1]=(short)f2bf(a0[1]); c0[2]=(short)f2bf(a0[2]); c0[3]=(short)f2bf(a0[3]);
            c0[4]=(short)f2bf(a1[0]); c0[5]=(short)f2bf(a1[1]); c0[6]=(short)f2bf(a1[2]); c0[7]=(short)f2bf(a1[3]);
            c1[0]=(short)f2bf(a2[0]); c1[1]=(short)f2bf(a2[1]); c1[2]=(short)f2bf(a2[2]); c1[3]=(short)f2bf(a2[3]);
            c1[4]=(short)f2bf(a3[0]); c1[5]=(short)f2bf(a3[1]); c1[6]=(short)f2bf(a3[2]); c1[7]=(short)f2bf(a3[3]);
            *(short8*)&As[bf ^ 1][r0 * 32 + (lane & 3) * 8] = c0;
            *(short8*)&As[bf ^ 1][r1 * 32 + (lane & 3) * 8] = c1;
        }
    }

    // epilogue: D row=(lane>>4)*4+reg (h), col=lane&15 (l)
    #pragma unroll
    for (int m = 0; m < 4; ++m) {
        const int h = h0 + wm * 64 + m * 16 + lk * 4;
        #pragma unroll
        for (int n = 0; n < 4; ++n) {
            const int l = l0 + wn * 64 + n * 16 + lr;
            #pragma unroll
            for (int r = 0; r < 4; ++r) {
                float v = acc[m][n][r] + bias[h + r];
                klin[((size_t)b * DM + h + r) * L_SEQ + l] = f2bf(v);
            }
        }
    }
}

// ---------------- expand: FIR + dot-form state expansion ----------------
__global__ __launch_bounds__(256, 4) void expand(
    const unsigned short* __restrict__ klin,
    const float* __restrict__ shift_B, const float* __restrict__ shift_C,
    const float* __restrict__ ssm_k_D, const float* __restrict__ log_dt,
    const float* __restrict__ log_A_real, const float* __restrict__ A_imag,
    const float* __restrict__ B_re, const float* __restrict__ B_im,
    float* __restrict__ out)
{
    __shared__ float sm[2112 + 2048 + 192];
    float* kl  = sm;           // 2112 (64 zeros + 2048)
    float* kk  = sm + 2112;    // 2048
    float* Fs  = sm + 4160;    // 64
    float* Bsh = sm + 4224;    // 64
    float* Csh = sm + 4288;    // 64
    float* ctb = sm;           // reuse kl region after FIR (needs 1024 floats)

    const int h = blockIdx.x, b = blockIdx.y;
    const int t = threadIdx.x;

    if (t < 64) {
        Bsh[t] = shift_B[h * 64 + t];
        Csh[t] = shift_C[h * 64 + t];
        kl[t] = 0.f;
    }
    {   // stage klin row (bf16 -> f32)
        const unsigned short* kr = klin + ((size_t)(b * DM + h)) * L_SEQ + t * 8;
        short8 v = *(const short8*)kr;
        #pragma unroll
        for (int e = 0; e < 8; ++e)
            kl[64 + t * 8 + e] = bf2f((unsigned short)v[e]);
    }
    __syncthreads();
    if (t < 64) {   // shift-kernel taps F[m] = sum_j C[j+m] B[j] (+D at m=0)
        float f = (t == 0) ? ssm_k_D[h] : 0.f;
        for (int j = 0; j + t < 64; ++j) f = fmaf(Csh[j + t], Bsh[j], f);
        Fs[t] = f;
    }
    __syncthreads();

    // FIR: thread t computes kk[8t..8t+7]; aligned-float4 sliding window
    {
        float acc8[8] = {0.f,0.f,0.f,0.f,0.f,0.f,0.f,0.f};
        const int base = 64 + t * 8;
        f32x4 W1 = *(const f32x4*)&kl[base];
        f32x4 W2 = *(const f32x4*)&kl[base + 4];
        #pragma unroll
        for (int q = 0; q < 16; ++q) {
            f32x4 W0 = *(const f32x4*)&kl[base - 4 * q - 4];
            f32x4 Fq = *(const f32x4*)&Fs[4 * q];
            float wb[12] = {W0[0],W0[1],W0[2],W0[3], W1[0],W1[1],W1[2],W1[3],
                            W2[0],W2[1],W2[2],W2[3]};
            #pragma unroll
            for (int r = 0; r < 4; ++r)
                #pragma unroll
                for (int c = 0; c < 8; ++c)
                    acc8[c] = fmaf(Fq[r], wb[4 + c - r], acc8[c]);
            W2 = W1; W1 = W0;
        }
        #pragma unroll
        for (int c = 0; c < 8; ++c) kk[t * 8 + c] = acc8[c];
    }
    __syncthreads();   // kk ready; all kl reads done -> ctb region reusable

    // per-(h,n) discretization
    const int n = t & 63, rg = t >> 6;
    const float dtv  = expf(log_dt[h]);
    const float Are  = -expf(log_A_real[h * 64 + n]);
    const float Aim  = A_imag[h * 64 + n];
    const float lre  = dtv * Are, lim = dtv * Aim;
    const float er   = expf(lre);
    float sI, cI; sincosf(lim, &sI, &cI);
    const float wr = er * cI, wi = er * sI;
    const float w2r = wr*wr - wi*wi,   w2i = 2.f*wr*wi;
    const float w4r = w2r*w2r - w2i*w2i, w4i = 2.f*w2r*w2i;
    const float w8r = w4r*w4r - w4i*w4i, w8i = 2.f*w4r*w4i;

    // contrib[r] = sum_i w^(255-i) kk[256r+i], r = 2*rg, 2*rg+1
    {
        const int r0 = rg * 2;
        const float* k0 = kk + r0 * 256;
        const float* k1 = k0 + 256;
        float pr = 1.f, pi = 0.f;
        float c0r = 0.f, c0i = 0.f, c1r = 0.f, c1i = 0.f;
        for (int g = 31; g >= 0; --g) {
            f32x4 x0 = *(const f32x4*)(k0 + g * 8);
            f32x4 x1 = *(const f32x4*)(k0 + g * 8 + 4);
            f32x4 y0 = *(const f32x4*)(k1 + g * 8);
            f32x4 y1 = *(const f32x4*)(k1 + g * 8 + 4);
            // S = v7 + w v6 + ... + w^7 v0 (8-elem Horner tree)
            float S0r, S0i, S1r, S1i;
            {
                float p76r = fmaf(wr, x1[2], x1[3]), p76i = wi * x1[2];
                float p54r = fmaf(wr, x1[0], x1[1]), p54i = wi * x1[0];
                float p32r = fmaf(wr, x0[2], x0[3]), p32i = wi * x0[2];
                float p10r = fmaf(wr, x0[0], x0[1]), p10i = wi * x0[0];
                float Hr = p76r + (w2r * p54r - w2i * p54i);
                float Hi = p76i + (w2r * p54i + w2i * p54r);
                float Lr = p32r + (w2r * p10r - w2i * p10i);
                float Li = p32i + (w2r * p10i + w2i * p10r);
                S0r = Hr + (w4r * Lr - w4i * Li);
                S0i = Hi + (w4r * Li + w4i * Lr);
            }
            {
                float p76r = fmaf(wr, y1[2], y1[3]), p76i = wi * y1[2];
                float p54r = fmaf(wr, y1[0], y1[1]), p54i = wi * y1[0];
                float p32r = fmaf(wr, y0[2], y0[3]), p32i = wi * y0[2];
                float p10r = fmaf(wr, y0[0], y0[1]), p10i = wi * y0[0];
                float Hr = p76r + (w2r * p54r - w2i * p54i);
                float Hi = p76i + (w2r * p54i + w2i * p54r);
                float Lr = p32r + (w2r * p10r - w2i * p10i);
                float Li = p32i + (w2r * p10i + w2i * p10r);
                S1r = Hr + (w4r * Lr - w4i * Li);
                S1i = Hi + (w4r * Li + w4i * Lr);
            }
            c0r = fmaf(pr, S0r, fmaf(-pi, S0i, c0r));
            c0i = fmaf(pr, S0i, fmaf( pi, S0r, c0i));
            c1r = fmaf(pr, S1r, fmaf(-pi, S1i, c1r));
            c1i = fmaf(pr, S1i, fmaf( pi, S1r, c1i));
            float tpr = pr * w8r - pi * w8i;
            pi = fmaf(pr, w8i, pi * w8r);
            pr = tpr;
        }
        ctb[(r0 * 64 + n) * 2]           = c0r;
        ctb[(r0 * 64 + n) * 2 + 1]       = c0i;
        ctb[((r0 + 1) * 64 + n) * 2]     = c1r;
        ctb[((r0 + 1) * 64 + n) * 2 + 1] = c1i;
    }
    __syncthreads();

    // scan over 8 chunks + dB readout (threads 0..63, n = t)
    if (t < 64) {
        float wHr = w8r, wHi = w8i;   // -> w^256 by 5 squarings
        #pragma unroll
        for (int s = 0; s < 5; ++s) {
            float nr = wHr * wHr - wHi * wHi;
            wHi = 2.f * wHr * wHi;
            wHr = nr;
        }
        const float den  = Are * Are + Aim * Aim;
        const float wm1r = wr - 1.f, wm1i = wi;
        const float tr_  = (wm1r * Are + wm1i * Aim) / den;
        const float ti_  = (wm1i * Are - wm1r * Aim) / den;
        const float br = B_re[h * 64 + n], bi = B_im[h * 64 + n];
        const float dBr = br * tr_ - bi * ti_;
        const float dBi = br * ti_ + bi * tr_;
        float sr = 0.f, si = 0.f;
        #pragma unroll
        for (int r = 0; r < 8; ++r) {
            float cr = ctb[(r * 64 + n) * 2];
            float ci = ctb[(r * 64 + n) * 2 + 1];
            float nsr = fmaf(wHr, sr, fmaf(-wHi, si, cr));
            float nsi = fmaf(wHr, si, fmaf( wHi, sr, ci));
            sr = nsr; si = nsi;
            out[(((size_t)b * NREC + r) * DM + h) * 64 + n] = dBr * sr - dBi * si;
        }
    }
}

extern "C" void kernel_launch(void* const* d_in, const int* in_sizes, int n_in,
                              void* d_out, int out_size, void* d_ws, size_t ws_size,
                              hipStream_t stream)
{
    const float* u       = (const float*)d_in[0];
    const float* W       = (const float*)d_in[1];
    const float* bias    = (const float*)d_in[2];
    const float* shift_B = (const float*)d_in[3];
    const float* shift_C = (const float*)d_in[4];
    const float* ssm_k_D = (const float*)d_in[5];
    const float* log_dt  = (const float*)d_in[6];
    const float* log_Ar  = (const float*)d_in[7];
    const float* A_imag  = (const float*)d_in[8];
    const float* B_re    = (const float*)d_in[9];
    const float* B_im    = (const float*)d_in[10];
    float* out = (float*)d_out;

    unsigned short* ub   = (unsigned short*)d_ws;                  // 32 MB
    unsigned short* klin = ub + (size_t)8 * L_SEQ * DM;            // 32 MB

    const int n_u = 8 * L_SEQ * DM;
    cvt_bf16<<<n_u / (256 * 8), 256, 0, stream>>>(u, ub, n_u);

    dim3 g1(L_SEQ / BN, DM / BM, 8);
    gemm_klin<<<g1, 256, 0, stream>>>(W, ub, bias, klin);

    dim3 g2(DM, 8);
    expand<<<g2, 256, 0, stream>>>(klin, shift_B, shift_C, ssm_k_D, log_dt,
                                   log_Ar, A_imag, B_re, B_im, out);
}

// Round 3
// 96.940 us; speedup vs baseline: 6.9286x; 2.1192x over previous
//
#include <hip/hip_runtime.h>
#include <cstddef>
#include <cstdint>

#define L_SEQ 2048
#define DM    1024
#define NREC  8
#define BM 128
#define BN 128
#define BK 32
#define NT (DM / BK)

typedef __attribute__((ext_vector_type(8))) short short8;
typedef __attribute__((ext_vector_type(4))) float f32x4;
typedef __attribute__((ext_vector_type(2))) unsigned int u32x2;

__device__ inline unsigned short f2bf(float f) {
    unsigned u = __float_as_uint(f);
    unsigned r = (u + 0x7FFFu + ((u >> 16) & 1u)) >> 16;
    return (unsigned short)r;
}
__device__ inline float bf2f(unsigned short s) {
    return __uint_as_float(((unsigned)s) << 16);
}
__device__ inline void gload_lds16(const void* g, void* l) {
    __builtin_amdgcn_global_load_lds(
        (const __attribute__((address_space(1))) void*)g,
        (__attribute__((address_space(3))) void*)l, 16, 0, 0);
}

// ---------------- u f32 -> bf16 ----------------
__global__ __launch_bounds__(256) void cvt_bf16(
    const float* __restrict__ in, unsigned short* __restrict__ out, int n)
{
    int i = (blockIdx.x * 256 + threadIdx.x) * 8;
    if (i >= n) return;
    f32x4 v0 = *(const f32x4*)(in + i);
    f32x4 v1 = *(const f32x4*)(in + i + 4);
    short8 o;
    o[0] = (short)f2bf(v0[0]); o[1] = (short)f2bf(v0[1]);
    o[2] = (short)f2bf(v0[2]); o[3] = (short)f2bf(v0[3]);
    o[4] = (short)f2bf(v1[0]); o[5] = (short)f2bf(v1[1]);
    o[6] = (short)f2bf(v1[2]); o[7] = (short)f2bf(v1[3]);
    *(short8*)(out + i) = o;
}

// ---------------- bf16 MFMA GEMM (unchanged from round 2) ----------------
__global__ __launch_bounds__(256, 2) void gemm_klin(
    const float* __restrict__ W, const unsigned short* __restrict__ ub,
    const float* __restrict__ bias, unsigned short* __restrict__ klin)
{
    __shared__ unsigned short As[2][BM * BK];
    __shared__ unsigned short Bs[2][BM * BK];
    const int b  = blockIdx.z;
    const int h0 = blockIdx.y * BM;
    const int l0 = blockIdx.x * BN;
    const int tid = threadIdx.x;
    const int lane = tid & 63, wv = tid >> 6;

    const int r0 = wv * 32 + (lane >> 2);
    const int r1 = r0 + 16;
    const int sw0 = (r0 ^ (r0 >> 2)) & 3;
    const int sw1 = (r1 ^ (r1 >> 2)) & 3;
    const int col0 = (((lane & 3) ^ sw0) << 3);
    const int col1 = (((lane & 3) ^ sw1) << 3);

    const unsigned short* gB0 = ub + ((size_t)(b * L_SEQ + l0 + r0)) * DM + col0;
    const unsigned short* gB1 = ub + ((size_t)(b * L_SEQ + l0 + r1)) * DM + col1;
    const float* gA0 = W + (size_t)(h0 + r0) * DM + col0;
    const float* gA1 = W + (size_t)(h0 + r1) * DM + col1;

    const int wm = wv >> 1, wn = wv & 1;
    const int lr = lane & 15, lk = lane >> 4;

    f32x4 acc[4][4];
    #pragma unroll
    for (int m = 0; m < 4; ++m)
        #pragma unroll
        for (int n = 0; n < 4; ++n) acc[m][n] = (f32x4){0.f, 0.f, 0.f, 0.f};

    gload_lds16(gB0, &Bs[0][(2 * wv) * 512]);
    gload_lds16(gB1, &Bs[0][(2 * wv + 1) * 512]);
    {
        f32x4 a0 = *(const f32x4*)(gA0);
        f32x4 a1 = *(const f32x4*)(gA0 + 4);
        f32x4 a2 = *(const f32x4*)(gA1);
        f32x4 a3 = *(const f32x4*)(gA1 + 4);
        short8 c0, c1;
        c0[0]=(short)f2bf(a0[0]); c0[1]=(short)f2bf(a0[1]); c0[2]=(short)f2bf(a0[2]); c0[3]=(short)f2bf(a0[3]);
        c0[4]=(short)f2bf(a1[0]); c0[5]=(short)f2bf(a1[1]); c0[6]=(short)f2bf(a1[2]); c0[7]=(short)f2bf(a1[3]);
        c1[0]=(short)f2bf(a2[0]); c1[1]=(short)f2bf(a2[1]); c1[2]=(short)f2bf(a2[2]); c1[3]=(short)f2bf(a2[3]);
        c1[4]=(short)f2bf(a3[0]); c1[5]=(short)f2bf(a3[1]); c1[6]=(short)f2bf(a3[2]); c1[7]=(short)f2bf(a3[3]);
        *(short8*)&As[0][r0 * 32 + (lane & 3) * 8] = c0;
        *(short8*)&As[0][r1 * 32 + (lane & 3) * 8] = c1;
    }

    for (int kt = 0; kt < NT; ++kt) {
        __syncthreads();
        const int bf = kt & 1;
        f32x4 a0, a1, a2, a3;
        const bool more = (kt + 1 < NT);
        if (more) {
            const int ko = (kt + 1) * BK;
            gload_lds16(gB0 + ko, &Bs[bf ^ 1][(2 * wv) * 512]);
            gload_lds16(gB1 + ko, &Bs[bf ^ 1][(2 * wv + 1) * 512]);
            a0 = *(const f32x4*)(gA0 + ko);
            a1 = *(const f32x4*)(gA0 + ko + 4);
            a2 = *(const f32x4*)(gA1 + ko);
            a3 = *(const f32x4*)(gA1 + ko + 4);
        }
        short8 af[4], bfr[4];
        #pragma unroll
        for (int m = 0; m < 4; ++m) {
            int row = wm * 64 + m * 16 + lr;
            int phys = lk ^ ((row ^ (row >> 2)) & 3);
            af[m] = *(const short8*)&As[bf][row * 32 + phys * 8];
        }
        #pragma unroll
        for (int n = 0; n < 4; ++n) {
            int row = wn * 64 + n * 16 + lr;
            int phys = lk ^ ((row ^ (row >> 2)) & 3);
            bfr[n] = *(const short8*)&Bs[bf][row * 32 + phys * 8];
        }
        #pragma unroll
        for (int m = 0; m < 4; ++m)
            #pragma unroll
            for (int n = 0; n < 4; ++n)
                acc[m][n] = __builtin_amdgcn_mfma_f32_16x16x32_bf16(af[m], bfr[n], acc[m][n], 0, 0, 0);
        if (more) {
            short8 c0, c1;
            c0[0]=(short)f2bf(a0[0]); c0[1]=(short)f2bf(a0[1]); c0[2]=(short)f2bf(a0[2]); c0[3]=(short)f2bf(a0[3]);
            c0[4]=(short)f2bf(a1[0]); c0[5]=(short)f2bf(a1[1]); c0[6]=(short)f2bf(a1[2]); c0[7]=(short)f2bf(a1[3]);
            c1[0]=(short)f2bf(a2[0]); c1[1]=(short)f2bf(a2[1]); c1[2]=(short)f2bf(a2[2]); c1[3]=(short)f2bf(a2[3]);
            c1[4]=(short)f2bf(a3[0]); c1[5]=(short)f2bf(a3[1]); c1[6]=(short)f2bf(a3[2]); c1[7]=(short)f2bf(a3[3]);
            *(short8*)&As[bf ^ 1][r0 * 32 + (lane & 3) * 8] = c0;
            *(short8*)&As[bf ^ 1][r1 * 32 + (lane & 3) * 8] = c1;
        }
    }

    #pragma unroll
    for (int m = 0; m < 4; ++m) {
        const int h = h0 + wm * 64 + m * 16 + lk * 4;
        #pragma unroll
        for (int n = 0; n < 4; ++n) {
            const int l = l0 + wn * 64 + n * 16 + lr;
            #pragma unroll
            for (int r = 0; r < 4; ++r) {
                float v = acc[m][n][r] + bias[h + r];
                klin[((size_t)b * DM + h + r) * L_SEQ + l] = f2bf(v);
            }
        }
    }
}

// ---------------- expand: MFMA FIR + MFMA state expansion ----------------
// LDS layout (bytes):
//  kl  [0,34816): 8 rows x 4352 (128B zero prefix + 4096 data + 128B zero tail), SWL-swizzled
//      (ctb overlays after FIR: re 64x68 f32 = 17408, im +17408)
//  kk  [34816,67584): 8 x 4096 bf16, SWK-swizzled
//  Afir[67584,70912): 16 x 208 bf16 (Toeplitz of taps, K=96 padded to 104)
//  Pre [70912,75008) / Pim [75008,79104): 64 x 32 bf16 (w^{31-j})
//  F   [79104,79360) f32 taps; Bsh/Csh next; w32 [79872,80384): 64 x (re,im) f32
__device__ inline void get_disc(const float* __restrict__ log_dt,
                                const float* __restrict__ lar,
                                const float* __restrict__ aim, int h, int n,
                                float& Are, float& Aim, float& lre, float& lim)
{
    float dtv = expf(log_dt[h]);
    Are = -expf(lar[h * 64 + n]);
    Aim = aim[h * 64 + n];
    lre = dtv * Are;
    lim = dtv * Aim;
}

__global__ __launch_bounds__(256, 2) void expand(
    const unsigned short* __restrict__ klin,
    const float* __restrict__ shift_B, const float* __restrict__ shift_C,
    const float* __restrict__ ssm_k_D, const float* __restrict__ log_dt,
    const float* __restrict__ log_A_real, const float* __restrict__ A_imag,
    const float* __restrict__ B_re, const float* __restrict__ B_im,
    float* __restrict__ out)
{
    __shared__ __align__(16) char sm[80384];
    constexpr int OKL = 0;
    constexpr int OKK = 34816;
    constexpr int OAF = 67584;
    constexpr int OPR = 70912;
    constexpr int OPI = 75008;
    constexpr int OF  = 79104;
    constexpr int OBS = 79360;
    constexpr int OCS = 79616;
    constexpr int OW32 = 79872;

    const int h = blockIdx.x;
    const int t = threadIdx.x;
    const int lane = t & 63, wv = t >> 6;

    // ---- stage: zeros (prefix+tail), klin rows via swizzled-source gload_lds ----
    {
        int q = lane & 15;
        int b = 2 * wv + (q >> 3);
        if (lane < 16)
            *(f32x4*)&sm[OKL + b * 4352 + (q & 7) * 16] = (f32x4){0.f, 0.f, 0.f, 0.f};
        else if (lane < 32)
            *(f32x4*)&sm[OKL + b * 4352 + 4224 + (q & 7) * 16] = (f32x4){0.f, 0.f, 0.f, 0.f};
    }
    #pragma unroll
    for (int rr = 0; rr < 2; ++rr) {
        const int b = 2 * wv + rr;
        const char* krow = (const char*)(klin + ((size_t)b * DM + h) * L_SEQ);
        const int s = (2 * b + 1 + (lane >> 3)) & 7;
        const int srcoff = (lane >> 3) * 128 + ((lane ^ s) & 7) * 16;
        #pragma unroll
        for (int c = 0; c < 4; ++c)
            gload_lds16(krow + c * 1024 + srcoff, &sm[OKL + b * 4352 + 128 + c * 1024]);
    }
    if (t < 64) {
        ((float*)&sm[OBS])[t] = shift_B[h * 64 + t];
        ((float*)&sm[OCS])[t] = shift_C[h * 64 + t];
        // w32 table
        float Are, Aim, lre, lim;
        get_disc(log_dt, log_A_real, A_imag, h, t, Are, Aim, lre, lim);
        float er = expf(32.f * lre);
        float sn, cs; sincosf(32.f * lim, &sn, &cs);
        ((float*)&sm[OW32])[t * 2]     = er * cs;
        ((float*)&sm[OW32])[t * 2 + 1] = er * sn;
    }
    {   // P32[n][j] = w_n^{31-j}, thread: n = t>>2, j-seg s = t&3
        int n = t >> 2, s4 = t & 3;
        float Are, Aim, lre, lim;
        get_disc(log_dt, log_A_real, A_imag, h, n, Are, Aim, lre, lim);
        float erw = expf(lre), snw, csw;
        sincosf(lim, &snw, &csw);
        float wr = erw * csw, wi = erw * snw;
        float e0 = (float)(24 - 8 * s4);
        float mag = expf(e0 * lre);
        float sn0, cs0; sincosf(e0 * lim, &sn0, &cs0);
        float pr = mag * cs0, pi = mag * sn0;   // w^{24-8s}
        float vr[8], vi[8];
        vr[7] = pr; vi[7] = pi;
        #pragma unroll
        for (int k = 6; k >= 0; --k) {
            float nr = pr * wr - pi * wi;
            pi = fmaf(pr, wi, pi * wr);
            pr = nr;
            vr[k] = pr; vi[k] = pi;
        }
        short8 re8, im8;
        #pragma unroll
        for (int e = 0; e < 8; ++e) {
            re8[e] = (short)f2bf(vr[e]);
            im8[e] = (short)f2bf(vi[e]);
        }
        *(short8*)&sm[OPR + t * 16] = re8;
        *(short8*)&sm[OPI + t * 16] = im8;
    }
    __syncthreads();   // kl staged, Bsh/Csh/P32/w32 ready

    if (t < 64) {   // taps F[m] = sum_j C[j+m] B[j] (+D at m=0)
        const float* Bp = (const float*)&sm[OBS];
        const float* Cp = (const float*)&sm[OCS];
        float f = (t == 0) ? ssm_k_D[h] : 0.f;
        for (int j = 0; j + t < 64; ++j) f = fmaf(Cp[j + t], Bp[j], f);
        ((float*)&sm[OF])[t] = f;
    }
    __syncthreads();   // F ready

    {   // Afir[i][k] = F[64+i-k] (0 outside), rows stride 104 bf16
        int i = t >> 4, ks = t & 15;
        if (ks < 12) {
            const float* Fp = (const float*)&sm[OF];
            short8 row;
            #pragma unroll
            for (int e = 0; e < 8; ++e) {
                int k = ks * 8 + e;
                int m = 64 + i - k;
                float v = (m >= 0 && m < 64) ? Fp[m] : 0.f;
                row[e] = (short)f2bf(v);
            }
            *(short8*)&sm[OAF + i * 208 + ks * 16] = row;
        }
    }
    __syncthreads();   // Afir ready

    // ---- FIR via MFMA: kk[b][l] ----
    {
        short8 afr[3];
        #pragma unroll
        for (int ks = 0; ks < 3; ++ks)
            afr[ks] = *(const short8*)&sm[OAF + (lane & 15) * 208 + ks * 64 + (lane >> 4) * 16];
        #pragma unroll
        for (int rr = 0; rr < 2; ++rr) {
            const int b = 2 * wv + rr;
            #pragma unroll
            for (int jg = 0; jg < 8; ++jg) {
                f32x4 d = (f32x4){0.f, 0.f, 0.f, 0.f};
                #pragma unroll
                for (int ks = 0; ks < 3; ++ks) {
                    int o = b * 4352 + (jg * 256 + (lane & 15) * 16 + ks * 32 + (lane >> 4) * 8) * 2;
                    o ^= ((o >> 7) & 7) << 4;     // SWL
                    short8 bfrag = *(const short8*)&sm[OKL + o];
                    d = __builtin_amdgcn_mfma_f32_16x16x32_bf16(afr[ks], bfrag, d, 0, 0, 0);
                }
                unsigned pk0 = ((unsigned)f2bf(d[0])) | (((unsigned)f2bf(d[1])) << 16);
                unsigned pk1 = ((unsigned)f2bf(d[2])) | (((unsigned)f2bf(d[3])) << 16);
                int o2 = b * 4096 + jg * 512 + (lane & 15) * 32 + (lane >> 4) * 8;
                o2 ^= ((o2 >> 9) & 7) << 4;       // SWK
                *(u32x2*)&sm[OKK + o2] = (u32x2){pk0, pk1};
            }
        }
    }
    __syncthreads();   // kk ready, kl dead

    // ---- phase 2: contrib[n][(b,r)] via MFMA + w32-Horner over g ----
    {
        short8 par[4], pai[4];
        #pragma unroll
        for (int mt = 0; mt < 4; ++mt) {
            int o = (mt * 16 + (lane & 15)) * 64 + (lane >> 4) * 16;
            par[mt] = *(const short8*)&sm[OPR + o];
            pai[mt] = *(const short8*)&sm[OPI + o];
        }
        float w32r[16], w32i[16];
        #pragma unroll
        for (int mt = 0; mt < 4; ++mt)
            #pragma unroll
            for (int rg = 0; rg < 4; ++rg) {
                int n = mt * 16 + (lane >> 4) * 4 + rg;
                float2 ww = *(const float2*)&sm[OW32 + n * 8];
                w32r[mt * 4 + rg] = ww.x;
                w32i[mt * 4 + rg] = ww.y;
            }
        f32x4 cr[4], ci_[4];
        #pragma unroll
        for (int mt = 0; mt < 4; ++mt) {
            cr[mt] = (f32x4){0.f, 0.f, 0.f, 0.f};
            ci_[mt] = (f32x4){0.f, 0.f, 0.f, 0.f};
        }
        const int colb = 2 * wv + ((lane & 15) >> 3);
        const int colr = lane & 7;
        #pragma unroll
        for (int g = 0; g < 8; ++g) {
            int o = colb * 4096 + colr * 512 + g * 64 + (lane >> 4) * 16;
            o ^= ((o >> 9) & 7) << 4;             // SWK
            short8 kf = *(const short8*)&sm[OKK + o];
            #pragma unroll
            for (int mt = 0; mt < 4; ++mt) {
                f32x4 sre = __builtin_amdgcn_mfma_f32_16x16x32_bf16(par[mt], kf, (f32x4){0.f,0.f,0.f,0.f}, 0, 0, 0);
                f32x4 sim = __builtin_amdgcn_mfma_f32_16x16x32_bf16(pai[mt], kf, (f32x4){0.f,0.f,0.f,0.f}, 0, 0, 0);
                #pragma unroll
                for (int rg = 0; rg < 4; ++rg) {
                    float wr = w32r[mt * 4 + rg], wi = w32i[mt * 4 + rg];
                    float ncr = fmaf(cr[mt][rg], wr, fmaf(-ci_[mt][rg], wi, sre[rg]));
                    float nci = fmaf(cr[mt][rg], wi, fmaf(ci_[mt][rg], wr, sim[rg]));
                    cr[mt][rg] = ncr;
                    ci_[mt][rg] = nci;
                }
            }
        }
        // write contrib to ctb (overlays kl): rows n stride 68 f32
        #pragma unroll
        for (int mt = 0; mt < 4; ++mt)
            #pragma unroll
            for (int rg = 0; rg < 4; ++rg) {
                int n = mt * 16 + (lane >> 4) * 4 + rg;
                int col = wv * 16 + (lane & 15);
                ((float*)&sm[OKL])[n * 68 + col] = cr[mt][rg];
                ((float*)&sm[OKL + 17408])[n * 68 + col] = ci_[mt][rg];
            }
    }
    __syncthreads();   // ctb ready

    // ---- scan over 8 chunks + dB readout ----
    {
        const int n = t & 63;
        float Are, Aim, lre, lim;
        get_disc(log_dt, log_A_real, A_imag, h, n, Are, Aim, lre, lim);
        float er = expf(lre), sn, cs;
        sincosf(lim, &sn, &cs);
        float wr = er * cs, wi = er * sn;
        float2 w32v = *(const float2*)&sm[OW32 + n * 8];
        float ar = w32v.x, ai = w32v.y;      // -> w^256 by 3 squarings
        #pragma unroll
        for (int s = 0; s < 3; ++s) {
            float nr = ar * ar - ai * ai;
            ai = 2.f * ar * ai;
            ar = nr;
        }
        float den = Are * Are + Aim * Aim;
        float wm1r = wr - 1.f, wm1i = wi;
        float tr_ = (wm1r * Are + wm1i * Aim) / den;
        float ti_ = (wm1i * Are - wm1r * Aim) / den;
        float br = B_re[h * 64 + n], bi = B_im[h * 64 + n];
        float dBr = br * tr_ - bi * ti_;
        float dBi = br * ti_ + bi * tr_;
        #pragma unroll
        for (int half = 0; half < 2; ++half) {
            int b = (t >> 6) + 4 * half;
            const float* cre = (const float*)&sm[OKL] + n * 68 + b * 8;
            const float* cim = (const float*)&sm[OKL + 17408] + n * 68 + b * 8;
            float sr = 0.f, si_ = 0.f;
            #pragma unroll
            for (int r = 0; r < 8; ++r) {
                float nsr = fmaf(ar, sr, fmaf(-ai, si_, cre[r]));
                float nsi = fmaf(ar, si_, fmaf(ai, sr, cim[r]));
                sr = nsr; si_ = nsi;
                out[(((size_t)b * NREC + r) * DM + h) * 64 + n] = dBr * sr - dBi * si_;
            }
        }
    }
}

extern "C" void kernel_launch(void* const* d_in, const int* in_sizes, int n_in,
                              void* d_out, int out_size, void* d_ws, size_t ws_size,
                              hipStream_t stream)
{
    const float* u       = (const float*)d_in[0];
    const float* W       = (const float*)d_in[1];
    const float* bias    = (const float*)d_in[2];
    const float* shift_B = (const float*)d_in[3];
    const float* shift_C = (const float*)d_in[4];
    const float* ssm_k_D = (const float*)d_in[5];
    const float* log_dt  = (const float*)d_in[6];
    const float* log_Ar  = (const float*)d_in[7];
    const float* A_imag  = (const float*)d_in[8];
    const float* B_re    = (const float*)d_in[9];
    const float* B_im    = (const float*)d_in[10];
    float* out = (float*)d_out;

    unsigned short* ub   = (unsigned short*)d_ws;            // 32 MB
    unsigned short* klin = ub + (size_t)8 * L_SEQ * DM;      // 32 MB

    const int n_u = 8 * L_SEQ * DM;
    cvt_bf16<<<n_u / (256 * 8), 256, 0, stream>>>(u, ub, n_u);

    dim3 g1(L_SEQ / BN, DM / BM, 8);
    gemm_klin<<<g1, 256, 0, stream>>>(W, ub, bias, klin);

    expand<<<dim3(DM), 256, 0, stream>>>(klin, shift_B, shift_C, ssm_k_D, log_dt,
                                         log_Ar, A_imag, B_re, B_im, out);
}

// Round 4
// 90.626 us; speedup vs baseline: 7.4113x; 1.0697x over previous
//
#include <hip/hip_runtime.h>
#include <cstddef>
#include <cstdint>

#define L_SEQ 2048
#define DM    1024
#define NREC  8
#define BM 128
#define BN 128
#define BK 32
#define NT (DM / BK)

typedef __attribute__((ext_vector_type(8))) short short8;
typedef __attribute__((ext_vector_type(4))) float f32x4;
typedef __attribute__((ext_vector_type(2))) unsigned int u32x2;

__device__ inline unsigned short f2bf(float f) {
    unsigned u = __float_as_uint(f);
    unsigned r = (u + 0x7FFFu + ((u >> 16) & 1u)) >> 16;
    return (unsigned short)r;
}
__device__ inline float bf2f(unsigned short s) {
    return __uint_as_float(((unsigned)s) << 16);
}
__device__ inline void gload_lds16(const void* g, void* l) {
    __builtin_amdgcn_global_load_lds(
        (const __attribute__((address_space(1))) void*)g,
        (__attribute__((address_space(3))) void*)l, 16, 0, 0);
}

// ---------------- f32 -> bf16 for u (na elems) and optionally W (nb elems) ----
__global__ __launch_bounds__(256) void cvt2_bf16(
    const float* __restrict__ a, unsigned short* __restrict__ oa, int na,
    const float* __restrict__ b, unsigned short* __restrict__ ob, int nb)
{
    int i = (blockIdx.x * 256 + threadIdx.x) * 8;
    const float* src;
    unsigned short* dst;
    if (i < na) { src = a + i; dst = oa + i; }
    else {
        int j = i - na;
        if (j >= nb) return;
        src = b + j; dst = ob + j;
    }
    f32x4 v0 = *(const f32x4*)(src);
    f32x4 v1 = *(const f32x4*)(src + 4);
    short8 o;
    o[0] = (short)f2bf(v0[0]); o[1] = (short)f2bf(v0[1]);
    o[2] = (short)f2bf(v0[2]); o[3] = (short)f2bf(v0[3]);
    o[4] = (short)f2bf(v1[0]); o[5] = (short)f2bf(v1[1]);
    o[6] = (short)f2bf(v1[2]); o[7] = (short)f2bf(v1[3]);
    *(short8*)dst = o;
}

// ---------------- bf16 MFMA GEMM: klin[b][h][l] = sum_d W[h][d] u[b][l][d] + bias[h]
// PREW: A staged via global_load_lds from pre-converted Wb (pure m97 K-loop).
// !PREW: round-3 fallback (in-kernel f32->bf16 A conversion).
template<bool PREW>
__global__ __launch_bounds__(256, 2) void gemm_klin(
    const float* __restrict__ Wf, const unsigned short* __restrict__ Wb,
    const unsigned short* __restrict__ ub,
    const float* __restrict__ bias, unsigned short* __restrict__ klin)
{
    __shared__ unsigned short As[2][BM * BK];
    __shared__ unsigned short Bs[2][BM * BK];
    // bijective XCD swizzle: XCD x gets contiguous wg range; b-major so one
    // XCD works one batch (u[b] 4MB + W 2MB ~ its private L2)
    int wg = (int)blockIdx.x;
    wg = (wg & 7) * 128 + (wg >> 3);
    const int b  = wg >> 7;
    const int h0 = ((wg >> 4) & 7) * BM;
    const int l0 = (wg & 15) * BN;
    const int tid = threadIdx.x;
    const int lane = tid & 63, wv = tid >> 6;

    // staging geometry: wave wv covers rows [32wv,32wv+32); dest linear,
    // source col XOR-pre-swizzled (rule 21 both-sides involution)
    const int r0 = wv * 32 + (lane >> 2);
    const int r1 = r0 + 16;
    const int sw0 = (r0 ^ (r0 >> 2)) & 3;
    const int sw1 = (r1 ^ (r1 >> 2)) & 3;
    const int col0 = (((lane & 3) ^ sw0) << 3);
    const int col1 = (((lane & 3) ^ sw1) << 3);

    const unsigned short* gB0 = ub + ((size_t)(b * L_SEQ + l0 + r0)) * DM + col0;
    const unsigned short* gB1 = ub + ((size_t)(b * L_SEQ + l0 + r1)) * DM + col1;
    const unsigned short* gA0b = Wb + (size_t)(h0 + r0) * DM + col0;
    const unsigned short* gA1b = Wb + (size_t)(h0 + r1) * DM + col1;
    const float* gA0f = Wf + (size_t)(h0 + r0) * DM + col0;
    const float* gA1f = Wf + (size_t)(h0 + r1) * DM + col1;

    const int wm = wv >> 1, wn = wv & 1;
    const int lr = lane & 15, lk = lane >> 4;

    f32x4 acc[4][4];
    #pragma unroll
    for (int m = 0; m < 4; ++m)
        #pragma unroll
        for (int n = 0; n < 4; ++n) acc[m][n] = (f32x4){0.f, 0.f, 0.f, 0.f};

    // prologue: stage tile 0
    gload_lds16(gB0, &Bs[0][(2 * wv) * 512]);
    gload_lds16(gB1, &Bs[0][(2 * wv + 1) * 512]);
    if constexpr (PREW) {
        gload_lds16(gA0b, &As[0][(2 * wv) * 512]);
        gload_lds16(gA1b, &As[0][(2 * wv + 1) * 512]);
    } else {
        f32x4 a0 = *(const f32x4*)(gA0f);
        f32x4 a1 = *(const f32x4*)(gA0f + 4);
        f32x4 a2 = *(const f32x4*)(gA1f);
        f32x4 a3 = *(const f32x4*)(gA1f + 4);
        short8 c0, c1;
        c0[0]=(short)f2bf(a0[0]); c0[1]=(short)f2bf(a0[1]); c0[2]=(short)f2bf(a0[2]); c0[3]=(short)f2bf(a0[3]);
        c0[4]=(short)f2bf(a1[0]); c0[5]=(short)f2bf(a1[1]); c0[6]=(short)f2bf(a1[2]); c0[7]=(short)f2bf(a1[3]);
        c1[0]=(short)f2bf(a2[0]); c1[1]=(short)f2bf(a2[1]); c1[2]=(short)f2bf(a2[2]); c1[3]=(short)f2bf(a2[3]);
        c1[4]=(short)f2bf(a3[0]); c1[5]=(short)f2bf(a3[1]); c1[6]=(short)f2bf(a3[2]); c1[7]=(short)f2bf(a3[3]);
        *(short8*)&As[0][r0 * 32 + (lane & 3) * 8] = c0;
        *(short8*)&As[0][r1 * 32 + (lane & 3) * 8] = c1;
    }

    for (int kt = 0; kt < NT; ++kt) {
        __syncthreads();   // buf[kt&1] staged (sync drains vmcnt+lgkmcnt)
        const int bf = kt & 1;
        const bool more = (kt + 1 < NT);
        f32x4 a0, a1, a2, a3;
        if (more) {
            const int ko = (kt + 1) * BK;
            gload_lds16(gB0 + ko, &Bs[bf ^ 1][(2 * wv) * 512]);
            gload_lds16(gB1 + ko, &Bs[bf ^ 1][(2 * wv + 1) * 512]);
            if constexpr (PREW) {
                gload_lds16(gA0b + ko, &As[bf ^ 1][(2 * wv) * 512]);
                gload_lds16(gA1b + ko, &As[bf ^ 1][(2 * wv + 1) * 512]);
            } else {
                a0 = *(const f32x4*)(gA0f + ko);
                a1 = *(const f32x4*)(gA0f + ko + 4);
                a2 = *(const f32x4*)(gA1f + ko);
                a3 = *(const f32x4*)(gA1f + ko + 4);
            }
        }
        short8 af[4], bfr[4];
        #pragma unroll
        for (int m = 0; m < 4; ++m) {
            int row = wm * 64 + m * 16 + lr;
            int phys = lk ^ ((row ^ (row >> 2)) & 3);
            af[m] = *(const short8*)&As[bf][row * 32 + phys * 8];
        }
        #pragma unroll
        for (int n = 0; n < 4; ++n) {
            int row = wn * 64 + n * 16 + lr;
            int phys = lk ^ ((row ^ (row >> 2)) & 3);
            bfr[n] = *(const short8*)&Bs[bf][row * 32 + phys * 8];
        }
        #pragma unroll
        for (int m = 0; m < 4; ++m)
            #pragma unroll
            for (int n = 0; n < 4; ++n)
                acc[m][n] = __builtin_amdgcn_mfma_f32_16x16x32_bf16(af[m], bfr[n], acc[m][n], 0, 0, 0);
        if constexpr (!PREW) {
            if (more) {
                short8 c0, c1;
                c0[0]=(short)f2bf(a0[0]); c0[1]=(short)f2bf(a0[1]); c0[2]=(short)f2bf(a0[2]); c0[3]=(short)f2bf(a0[3]);
                c0[4]=(short)f2bf(a1[0]); c0[5]=(short)f2bf(a1[1]); c0[6]=(short)f2bf(a1[2]); c0[7]=(short)f2bf(a1[3]);
                c1[0]=(short)f2bf(a2[0]); c1[1]=(short)f2bf(a2[1]); c1[2]=(short)f2bf(a2[2]); c1[3]=(short)f2bf(a2[3]);
                c1[4]=(short)f2bf(a3[0]); c1[5]=(short)f2bf(a3[1]); c1[6]=(short)f2bf(a3[2]); c1[7]=(short)f2bf(a3[3]);
                *(short8*)&As[bf ^ 1][r0 * 32 + (lane & 3) * 8] = c0;
                *(short8*)&As[bf ^ 1][r1 * 32 + (lane & 3) * 8] = c1;
            }
        }
    }

    // epilogue: D row=(lane>>4)*4+reg (h), col=lane&15 (l)
    #pragma unroll
    for (int m = 0; m < 4; ++m) {
        const int h = h0 + wm * 64 + m * 16 + lk * 4;
        #pragma unroll
        for (int n = 0; n < 4; ++n) {
            const int l = l0 + wn * 64 + n * 16 + lr;
            #pragma unroll
            for (int r = 0; r < 4; ++r) {
                float v = acc[m][n][r] + bias[h + r];
                klin[((size_t)b * DM + h + r) * L_SEQ + l] = f2bf(v);
            }
        }
    }
}

// ---------------- expand: MFMA FIR + MFMA state expansion (unchanged r3) ----
__device__ inline void get_disc(const float* __restrict__ log_dt,
                                const float* __restrict__ lar,
                                const float* __restrict__ aim, int h, int n,
                                float& Are, float& Aim, float& lre, float& lim)
{
    float dtv = expf(log_dt[h]);
    Are = -expf(lar[h * 64 + n]);
    Aim = aim[h * 64 + n];
    lre = dtv * Are;
    lim = dtv * Aim;
}

__global__ __launch_bounds__(256, 2) void expand(
    const unsigned short* __restrict__ klin,
    const float* __restrict__ shift_B, const float* __restrict__ shift_C,
    const float* __restrict__ ssm_k_D, const float* __restrict__ log_dt,
    const float* __restrict__ log_A_real, const float* __restrict__ A_imag,
    const float* __restrict__ B_re, const float* __restrict__ B_im,
    float* __restrict__ out)
{
    __shared__ __align__(16) char sm[80384];
    constexpr int OKL = 0;
    constexpr int OKK = 34816;
    constexpr int OAF = 67584;
    constexpr int OPR = 70912;
    constexpr int OPI = 75008;
    constexpr int OF  = 79104;
    constexpr int OBS = 79360;
    constexpr int OCS = 79616;
    constexpr int OW32 = 79872;

    const int h = blockIdx.x;
    const int t = threadIdx.x;
    const int lane = t & 63, wv = t >> 6;

    {
        int q = lane & 15;
        int b = 2 * wv + (q >> 3);
        if (lane < 16)
            *(f32x4*)&sm[OKL + b * 4352 + (q & 7) * 16] = (f32x4){0.f, 0.f, 0.f, 0.f};
        else if (lane < 32)
            *(f32x4*)&sm[OKL + b * 4352 + 4224 + (q & 7) * 16] = (f32x4){0.f, 0.f, 0.f, 0.f};
    }
    #pragma unroll
    for (int rr = 0; rr < 2; ++rr) {
        const int b = 2 * wv + rr;
        const char* krow = (const char*)(klin + ((size_t)b * DM + h) * L_SEQ);
        const int s = (2 * b + 1 + (lane >> 3)) & 7;
        const int srcoff = (lane >> 3) * 128 + ((lane ^ s) & 7) * 16;
        #pragma unroll
        for (int c = 0; c < 4; ++c)
            gload_lds16(krow + c * 1024 + srcoff, &sm[OKL + b * 4352 + 128 + c * 1024]);
    }
    if (t < 64) {
        ((float*)&sm[OBS])[t] = shift_B[h * 64 + t];
        ((float*)&sm[OCS])[t] = shift_C[h * 64 + t];
        float Are, Aim, lre, lim;
        get_disc(log_dt, log_A_real, A_imag, h, t, Are, Aim, lre, lim);
        float er = expf(32.f * lre);
        float sn, cs; sincosf(32.f * lim, &sn, &cs);
        ((float*)&sm[OW32])[t * 2]     = er * cs;
        ((float*)&sm[OW32])[t * 2 + 1] = er * sn;
    }
    {
        int n = t >> 2, s4 = t & 3;
        float Are, Aim, lre, lim;
        get_disc(log_dt, log_A_real, A_imag, h, n, Are, Aim, lre, lim);
        float erw = expf(lre), snw, csw;
        sincosf(lim, &snw, &csw);
        float wr = erw * csw, wi = erw * snw;
        float e0 = (float)(24 - 8 * s4);
        float mag = expf(e0 * lre);
        float sn0, cs0; sincosf(e0 * lim, &sn0, &cs0);
        float pr = mag * cs0, pi = mag * sn0;
        float vr[8], vi[8];
        vr[7] = pr; vi[7] = pi;
        #pragma unroll
        for (int k = 6; k >= 0; --k) {
            float nr = pr * wr - pi * wi;
            pi = fmaf(pr, wi, pi * wr);
            pr = nr;
            vr[k] = pr; vi[k] = pi;
        }
        short8 re8, im8;
        #pragma unroll
        for (int e = 0; e < 8; ++e) {
            re8[e] = (short)f2bf(vr[e]);
            im8[e] = (short)f2bf(vi[e]);
        }
        *(short8*)&sm[OPR + t * 16] = re8;
        *(short8*)&sm[OPI + t * 16] = im8;
    }
    __syncthreads();

    if (t < 64) {
        const float* Bp = (const float*)&sm[OBS];
        const float* Cp = (const float*)&sm[OCS];
        float f = (t == 0) ? ssm_k_D[h] : 0.f;
        for (int j = 0; j + t < 64; ++j) f = fmaf(Cp[j + t], Bp[j], f);
        ((float*)&sm[OF])[t] = f;
    }
    __syncthreads();

    {
        int i = t >> 4, ks = t & 15;
        if (ks < 12) {
            const float* Fp = (const float*)&sm[OF];
            short8 row;
            #pragma unroll
            for (int e = 0; e < 8; ++e) {
                int k = ks * 8 + e;
                int m = 64 + i - k;
                float v = (m >= 0 && m < 64) ? Fp[m] : 0.f;
                row[e] = (short)f2bf(v);
            }
            *(short8*)&sm[OAF + i * 208 + ks * 16] = row;
        }
    }
    __syncthreads();

    {
        short8 afr[3];
        #pragma unroll
        for (int ks = 0; ks < 3; ++ks)
            afr[ks] = *(const short8*)&sm[OAF + (lane & 15) * 208 + ks * 64 + (lane >> 4) * 16];
        #pragma unroll
        for (int rr = 0; rr < 2; ++rr) {
            const int b = 2 * wv + rr;
            #pragma unroll
            for (int jg = 0; jg < 8; ++jg) {
                f32x4 d = (f32x4){0.f, 0.f, 0.f, 0.f};
                #pragma unroll
                for (int ks = 0; ks < 3; ++ks) {
                    int o = b * 4352 + (jg * 256 + (lane & 15) * 16 + ks * 32 + (lane >> 4) * 8) * 2;
                    o ^= ((o >> 7) & 7) << 4;     // SWL
                    short8 bfrag = *(const short8*)&sm[OKL + o];
                    d = __builtin_amdgcn_mfma_f32_16x16x32_bf16(afr[ks], bfrag, d, 0, 0, 0);
                }
                unsigned pk0 = ((unsigned)f2bf(d[0])) | (((unsigned)f2bf(d[1])) << 16);
                unsigned pk1 = ((unsigned)f2bf(d[2])) | (((unsigned)f2bf(d[3])) << 16);
                int o2 = b * 4096 + jg * 512 + (lane & 15) * 32 + (lane >> 4) * 8;
                o2 ^= ((o2 >> 9) & 7) << 4;       // SWK
                *(u32x2*)&sm[OKK + o2] = (u32x2){pk0, pk1};
            }
        }
    }
    __syncthreads();

    {
        short8 par[4], pai[4];
        #pragma unroll
        for (int mt = 0; mt < 4; ++mt) {
            int o = (mt * 16 + (lane & 15)) * 64 + (lane >> 4) * 16;
            par[mt] = *(const short8*)&sm[OPR + o];
            pai[mt] = *(const short8*)&sm[OPI + o];
        }
        float w32r[16], w32i[16];
        #pragma unroll
        for (int mt = 0; mt < 4; ++mt)
            #pragma unroll
            for (int rg = 0; rg < 4; ++rg) {
                int n = mt * 16 + (lane >> 4) * 4 + rg;
                float2 ww = *(const float2*)&sm[OW32 + n * 8];
                w32r[mt * 4 + rg] = ww.x;
                w32i[mt * 4 + rg] = ww.y;
            }
        f32x4 cr[4], ci_[4];
        #pragma unroll
        for (int mt = 0; mt < 4; ++mt) {
            cr[mt] = (f32x4){0.f, 0.f, 0.f, 0.f};
            ci_[mt] = (f32x4){0.f, 0.f, 0.f, 0.f};
        }
        const int colb = 2 * wv + ((lane & 15) >> 3);
        const int colr = lane & 7;
        #pragma unroll
        for (int g = 0; g < 8; ++g) {
            int o = colb * 4096 + colr * 512 + g * 64 + (lane >> 4) * 16;
            o ^= ((o >> 9) & 7) << 4;             // SWK
            short8 kf = *(const short8*)&sm[OKK + o];
            #pragma unroll
            for (int mt = 0; mt < 4; ++mt) {
                f32x4 sre = __builtin_amdgcn_mfma_f32_16x16x32_bf16(par[mt], kf, (f32x4){0.f,0.f,0.f,0.f}, 0, 0, 0);
                f32x4 sim = __builtin_amdgcn_mfma_f32_16x16x32_bf16(pai[mt], kf, (f32x4){0.f,0.f,0.f,0.f}, 0, 0, 0);
                #pragma unroll
                for (int rg = 0; rg < 4; ++rg) {
                    float wr = w32r[mt * 4 + rg], wi = w32i[mt * 4 + rg];
                    float ncr = fmaf(cr[mt][rg], wr, fmaf(-ci_[mt][rg], wi, sre[rg]));
                    float nci = fmaf(cr[mt][rg], wi, fmaf(ci_[mt][rg], wr, sim[rg]));
                    cr[mt][rg] = ncr;
                    ci_[mt][rg] = nci;
                }
            }
        }
        #pragma unroll
        for (int mt = 0; mt < 4; ++mt)
            #pragma unroll
            for (int rg = 0; rg < 4; ++rg) {
                int n = mt * 16 + (lane >> 4) * 4 + rg;
                int col = wv * 16 + (lane & 15);
                ((float*)&sm[OKL])[n * 68 + col] = cr[mt][rg];
                ((float*)&sm[OKL + 17408])[n * 68 + col] = ci_[mt][rg];
            }
    }
    __syncthreads();

    {
        const int n = t & 63;
        float Are, Aim, lre, lim;
        get_disc(log_dt, log_A_real, A_imag, h, n, Are, Aim, lre, lim);
        float er = expf(lre), sn, cs;
        sincosf(lim, &sn, &cs);
        float wr = er * cs, wi = er * sn;
        float2 w32v = *(const float2*)&sm[OW32 + n * 8];
        float ar = w32v.x, ai = w32v.y;
        #pragma unroll
        for (int s = 0; s < 3; ++s) {
            float nr = ar * ar - ai * ai;
            ai = 2.f * ar * ai;
            ar = nr;
        }
        float den = Are * Are + Aim * Aim;
        float wm1r = wr - 1.f, wm1i = wi;
        float tr_ = (wm1r * Are + wm1i * Aim) / den;
        float ti_ = (wm1i * Are - wm1r * Aim) / den;
        float br = B_re[h * 64 + n], bi = B_im[h * 64 + n];
        float dBr = br * tr_ - bi * ti_;
        float dBi = br * ti_ + bi * tr_;
        #pragma unroll
        for (int half = 0; half < 2; ++half) {
            int b = (t >> 6) + 4 * half;
            const float* cre = (const float*)&sm[OKL] + n * 68 + b * 8;
            const float* cim = (const float*)&sm[OKL + 17408] + n * 68 + b * 8;
            float sr = 0.f, si_ = 0.f;
            #pragma unroll
            for (int r = 0; r < 8; ++r) {
                float nsr = fmaf(ar, sr, fmaf(-ai, si_, cre[r]));
                float nsi = fmaf(ar, si_, fmaf(ai, sr, cim[r]));
                sr = nsr; si_ = nsi;
                out[(((size_t)b * NREC + r) * DM + h) * 64 + n] = dBr * sr - dBi * si_;
            }
        }
    }
}

extern "C" void kernel_launch(void* const* d_in, const int* in_sizes, int n_in,
                              void* d_out, int out_size, void* d_ws, size_t ws_size,
                              hipStream_t stream)
{
    const float* u       = (const float*)d_in[0];
    const float* W       = (const float*)d_in[1];
    const float* bias    = (const float*)d_in[2];
    const float* shift_B = (const float*)d_in[3];
    const float* shift_C = (const float*)d_in[4];
    const float* ssm_k_D = (const float*)d_in[5];
    const float* log_dt  = (const float*)d_in[6];
    const float* log_Ar  = (const float*)d_in[7];
    const float* A_imag  = (const float*)d_in[8];
    const float* B_re    = (const float*)d_in[9];
    const float* B_im    = (const float*)d_in[10];
    float* out = (float*)d_out;

    const int n_u = 8 * L_SEQ * DM;     // 16M elems
    const int n_w = DM * DM;            // 1M elems
    unsigned short* ub   = (unsigned short*)d_ws;            // [0, 32MB)
    unsigned short* klin = ub + (size_t)n_u;                 // [32MB, 64MB)
    unsigned short* Wb   = klin + (size_t)n_u;               // [64MB, 66MB)

    const bool prew = ws_size >= (size_t)66 * 1024 * 1024;

    if (prew) {
        cvt2_bf16<<<(n_u + n_w) / (256 * 8), 256, 0, stream>>>(u, ub, n_u, W, Wb, n_w);
        gemm_klin<true><<<dim3(1024), 256, 0, stream>>>(W, Wb, ub, bias, klin);
    } else {
        cvt2_bf16<<<n_u / (256 * 8), 256, 0, stream>>>(u, ub, n_u, W, Wb, 0);
        gemm_klin<false><<<dim3(1024), 256, 0, stream>>>(W, Wb, ub, bias, klin);
    }

    expand<<<dim3(DM), 256, 0, stream>>>(klin, shift_B, shift_C, ssm_k_D, log_dt,
                                         log_Ar, A_imag, B_re, B_im, out);
}

// Round 5
// 88.194 us; speedup vs baseline: 7.6157x; 1.0276x over previous
//
#include <hip/hip_runtime.h>
#include <cstddef>
#include <cstdint>

#define L_SEQ 2048
#define DM    1024
#define NREC  8
#define BM 128
#define BN 128
#define BK 32
#define NT (DM / BK)

typedef __attribute__((ext_vector_type(8))) short short8;
typedef __attribute__((ext_vector_type(4))) float f32x4;
typedef __attribute__((ext_vector_type(2))) unsigned int u32x2;

__device__ inline unsigned short f2bf(float f) {
    unsigned u = __float_as_uint(f);
    unsigned r = (u + 0x7FFFu + ((u >> 16) & 1u)) >> 16;
    return (unsigned short)r;
}
__device__ inline float bf2f(unsigned short s) {
    return __uint_as_float(((unsigned)s) << 16);
}
__device__ inline void gload_lds16(const void* g, void* l) {
    __builtin_amdgcn_global_load_lds(
        (const __attribute__((address_space(1))) void*)g,
        (__attribute__((address_space(3))) void*)l, 16, 0, 0);
}

// ---------------- f32 -> bf16 for u (na elems) and optionally W (nb elems) ----
__global__ __launch_bounds__(256) void cvt2_bf16(
    const float* __restrict__ a, unsigned short* __restrict__ oa, int na,
    const float* __restrict__ b, unsigned short* __restrict__ ob, int nb)
{
    int i = (blockIdx.x * 256 + threadIdx.x) * 8;
    const float* src;
    unsigned short* dst;
    if (i < na) { src = a + i; dst = oa + i; }
    else {
        int j = i - na;
        if (j >= nb) return;
        src = b + j; dst = ob + j;
    }
    f32x4 v0 = *(const f32x4*)(src);
    f32x4 v1 = *(const f32x4*)(src + 4);
    short8 o;
    o[0] = (short)f2bf(v0[0]); o[1] = (short)f2bf(v0[1]);
    o[2] = (short)f2bf(v0[2]); o[3] = (short)f2bf(v0[3]);
    o[4] = (short)f2bf(v1[0]); o[5] = (short)f2bf(v1[1]);
    o[6] = (short)f2bf(v1[2]); o[7] = (short)f2bf(v1[3]);
    *(short8*)dst = o;
}

// ---------------- bf16 MFMA GEMM (unchanged from round 4) ----------------
template<bool PREW>
__global__ __launch_bounds__(256, 2) void gemm_klin(
    const float* __restrict__ Wf, const unsigned short* __restrict__ Wb,
    const unsigned short* __restrict__ ub,
    const float* __restrict__ bias, unsigned short* __restrict__ klin)
{
    __shared__ unsigned short As[2][BM * BK];
    __shared__ unsigned short Bs[2][BM * BK];
    int wg = (int)blockIdx.x;
    wg = (wg & 7) * 128 + (wg >> 3);
    const int b  = wg >> 7;
    const int h0 = ((wg >> 4) & 7) * BM;
    const int l0 = (wg & 15) * BN;
    const int tid = threadIdx.x;
    const int lane = tid & 63, wv = tid >> 6;

    const int r0 = wv * 32 + (lane >> 2);
    const int r1 = r0 + 16;
    const int sw0 = (r0 ^ (r0 >> 2)) & 3;
    const int sw1 = (r1 ^ (r1 >> 2)) & 3;
    const int col0 = (((lane & 3) ^ sw0) << 3);
    const int col1 = (((lane & 3) ^ sw1) << 3);

    const unsigned short* gB0 = ub + ((size_t)(b * L_SEQ + l0 + r0)) * DM + col0;
    const unsigned short* gB1 = ub + ((size_t)(b * L_SEQ + l0 + r1)) * DM + col1;
    const unsigned short* gA0b = Wb + (size_t)(h0 + r0) * DM + col0;
    const unsigned short* gA1b = Wb + (size_t)(h0 + r1) * DM + col1;
    const float* gA0f = Wf + (size_t)(h0 + r0) * DM + col0;
    const float* gA1f = Wf + (size_t)(h0 + r1) * DM + col1;

    const int wm = wv >> 1, wn = wv & 1;
    const int lr = lane & 15, lk = lane >> 4;

    f32x4 acc[4][4];
    #pragma unroll
    for (int m = 0; m < 4; ++m)
        #pragma unroll
        for (int n = 0; n < 4; ++n) acc[m][n] = (f32x4){0.f, 0.f, 0.f, 0.f};

    gload_lds16(gB0, &Bs[0][(2 * wv) * 512]);
    gload_lds16(gB1, &Bs[0][(2 * wv + 1) * 512]);
    if constexpr (PREW) {
        gload_lds16(gA0b, &As[0][(2 * wv) * 512]);
        gload_lds16(gA1b, &As[0][(2 * wv + 1) * 512]);
    } else {
        f32x4 a0 = *(const f32x4*)(gA0f);
        f32x4 a1 = *(const f32x4*)(gA0f + 4);
        f32x4 a2 = *(const f32x4*)(gA1f);
        f32x4 a3 = *(const f32x4*)(gA1f + 4);
        short8 c0, c1;
        c0[0]=(short)f2bf(a0[0]); c0[1]=(short)f2bf(a0[1]); c0[2]=(short)f2bf(a0[2]); c0[3]=(short)f2bf(a0[3]);
        c0[4]=(short)f2bf(a1[0]); c0[5]=(short)f2bf(a1[1]); c0[6]=(short)f2bf(a1[2]); c0[7]=(short)f2bf(a1[3]);
        c1[0]=(short)f2bf(a2[0]); c1[1]=(short)f2bf(a2[1]); c1[2]=(short)f2bf(a2[2]); c1[3]=(short)f2bf(a2[3]);
        c1[4]=(short)f2bf(a3[0]); c1[5]=(short)f2bf(a3[1]); c1[6]=(short)f2bf(a3[2]); c1[7]=(short)f2bf(a3[3]);
        *(short8*)&As[0][r0 * 32 + (lane & 3) * 8] = c0;
        *(short8*)&As[0][r1 * 32 + (lane & 3) * 8] = c1;
    }

    for (int kt = 0; kt < NT; ++kt) {
        __syncthreads();
        const int bf = kt & 1;
        const bool more = (kt + 1 < NT);
        f32x4 a0, a1, a2, a3;
        if (more) {
            const int ko = (kt + 1) * BK;
            gload_lds16(gB0 + ko, &Bs[bf ^ 1][(2 * wv) * 512]);
            gload_lds16(gB1 + ko, &Bs[bf ^ 1][(2 * wv + 1) * 512]);
            if constexpr (PREW) {
                gload_lds16(gA0b + ko, &As[bf ^ 1][(2 * wv) * 512]);
                gload_lds16(gA1b + ko, &As[bf ^ 1][(2 * wv + 1) * 512]);
            } else {
                a0 = *(const f32x4*)(gA0f + ko);
                a1 = *(const f32x4*)(gA0f + ko + 4);
                a2 = *(const f32x4*)(gA1f + ko);
                a3 = *(const f32x4*)(gA1f + ko + 4);
            }
        }
        short8 af[4], bfr[4];
        #pragma unroll
        for (int m = 0; m < 4; ++m) {
            int row = wm * 64 + m * 16 + lr;
            int phys = lk ^ ((row ^ (row >> 2)) & 3);
            af[m] = *(const short8*)&As[bf][row * 32 + phys * 8];
        }
        #pragma unroll
        for (int n = 0; n < 4; ++n) {
            int row = wn * 64 + n * 16 + lr;
            int phys = lk ^ ((row ^ (row >> 2)) & 3);
            bfr[n] = *(const short8*)&Bs[bf][row * 32 + phys * 8];
        }
        #pragma unroll
        for (int m = 0; m < 4; ++m)
            #pragma unroll
            for (int n = 0; n < 4; ++n)
                acc[m][n] = __builtin_amdgcn_mfma_f32_16x16x32_bf16(af[m], bfr[n], acc[m][n], 0, 0, 0);
        if constexpr (!PREW) {
            if (more) {
                short8 c0, c1;
                c0[0]=(short)f2bf(a0[0]); c0[1]=(short)f2bf(a0[1]); c0[2]=(short)f2bf(a0[2]); c0[3]=(short)f2bf(a0[3]);
                c0[4]=(short)f2bf(a1[0]); c0[5]=(short)f2bf(a1[1]); c0[6]=(short)f2bf(a1[2]); c0[7]=(short)f2bf(a1[3]);
                c1[0]=(short)f2bf(a2[0]); c1[1]=(short)f2bf(a2[1]); c1[2]=(short)f2bf(a2[2]); c1[3]=(short)f2bf(a2[3]);
                c1[4]=(short)f2bf(a3[0]); c1[5]=(short)f2bf(a3[1]); c1[6]=(short)f2bf(a3[2]); c1[7]=(short)f2bf(a3[3]);
                *(short8*)&As[bf ^ 1][r0 * 32 + (lane & 3) * 8] = c0;
                *(short8*)&As[bf ^ 1][r1 * 32 + (lane & 3) * 8] = c1;
            }
        }
    }

    #pragma unroll
    for (int m = 0; m < 4; ++m) {
        const int h = h0 + wm * 64 + m * 16 + lk * 4;
        #pragma unroll
        for (int n = 0; n < 4; ++n) {
            const int l = l0 + wn * 64 + n * 16 + lr;
            #pragma unroll
            for (int r = 0; r < 4; ++r) {
                float v = acc[m][n][r] + bias[h + r];
                klin[((size_t)b * DM + h + r) * L_SEQ + l] = f2bf(v);
            }
        }
    }
}

// ---------------- expand: one block per (h, b-pair); 29.7KB LDS, 5 blocks/CU ----
// LDS (bytes):
//  kl  [0,8704):      2 rows x 4352 (128B zero prefix + 4096 data + 128B tail), SWL
//  kk  [8704,16896):  2 x 4096 bf16, SWK   (ctb overlays [8704,17408) after phase2)
//  Afir[16896,20224): 16 x 208B (Toeplitz taps)
//  Pre [20224,24320) / Pim [24320,28416): 64 x 32 bf16
//  F   [28416) 256B; Bs 28672; Cs 28928; w32 [29184,29696)
__device__ inline void get_disc(const float* __restrict__ log_dt,
                                const float* __restrict__ lar,
                                const float* __restrict__ aim, int h, int n,
                                float& Are, float& Aim, float& lre, float& lim)
{
    float dtv = expf(log_dt[h]);
    Are = -expf(lar[h * 64 + n]);
    Aim = aim[h * 64 + n];
    lre = dtv * Are;
    lim = dtv * Aim;
}

__global__ __launch_bounds__(256, 5) void expand(
    const unsigned short* __restrict__ klin,
    const float* __restrict__ shift_B, const float* __restrict__ shift_C,
    const float* __restrict__ ssm_k_D, const float* __restrict__ log_dt,
    const float* __restrict__ log_A_real, const float* __restrict__ A_imag,
    const float* __restrict__ B_re, const float* __restrict__ B_im,
    float* __restrict__ out)
{
    __shared__ __align__(16) char sm[29696];
    constexpr int OKL = 0;
    constexpr int OKK = 8704;
    constexpr int OAF = 16896;
    constexpr int OPR = 20224;
    constexpr int OPI = 24320;
    constexpr int OF  = 28416;
    constexpr int OBS = 28672;
    constexpr int OCS = 28928;
    constexpr int OW32 = 29184;

    const int h  = blockIdx.x;
    const int bg = blockIdx.y;      // b-pair index 0..3
    const int t = threadIdx.x;
    const int lane = t & 63, wv = t >> 6;

    // ---- zero prefix/tail: 2 rows x 2 regions x 8 x 16B ----
    if (t < 32) {
        int rl = t >> 4, reg = (t >> 3) & 1, idx = t & 7;
        *(f32x4*)&sm[OKL + rl * 4352 + reg * 4224 + idx * 16] = (f32x4){0.f, 0.f, 0.f, 0.f};
    }
    // ---- stage: wave wv -> row rl=wv>>1, half hf=wv&1 (2 gloads, swz source) ----
    {
        const int rl = wv >> 1, hf = wv & 1;
        const int b = bg * 2 + rl;
        const char* krow = (const char*)(klin + ((size_t)b * DM + h) * L_SEQ);
        const int s = (2 * rl + 1 + (lane >> 3)) & 7;
        const int so = hf * 2048 + (lane >> 3) * 128 + ((lane ^ s) & 7) * 16;
        gload_lds16(krow + so,        &sm[OKL + rl * 4352 + 128 + hf * 2048]);
        gload_lds16(krow + so + 1024, &sm[OKL + rl * 4352 + 128 + hf * 2048 + 1024]);
    }
    if (t < 64) {
        ((float*)&sm[OBS])[t] = shift_B[h * 64 + t];
        ((float*)&sm[OCS])[t] = shift_C[h * 64 + t];
        float Are, Aim, lre, lim;
        get_disc(log_dt, log_A_real, A_imag, h, t, Are, Aim, lre, lim);
        float er = expf(32.f * lre);
        float sn, cs; sincosf(32.f * lim, &sn, &cs);
        ((float*)&sm[OW32])[t * 2]     = er * cs;
        ((float*)&sm[OW32])[t * 2 + 1] = er * sn;
    }
    {   // P32[n][j] = w_n^{31-j}: n = t>>2, j-seg s4 = t&3
        int n = t >> 2, s4 = t & 3;
        float Are, Aim, lre, lim;
        get_disc(log_dt, log_A_real, A_imag, h, n, Are, Aim, lre, lim);
        float erw = expf(lre), snw, csw;
        sincosf(lim, &snw, &csw);
        float wr = erw * csw, wi = erw * snw;
        float e0 = (float)(24 - 8 * s4);
        float mag = expf(e0 * lre);
        float sn0, cs0; sincosf(e0 * lim, &sn0, &cs0);
        float pr = mag * cs0, pi = mag * sn0;
        float vr[8], vi[8];
        vr[7] = pr; vi[7] = pi;
        #pragma unroll
        for (int k = 6; k >= 0; --k) {
            float nr = pr * wr - pi * wi;
            pi = fmaf(pr, wi, pi * wr);
            pr = nr;
            vr[k] = pr; vi[k] = pi;
        }
        short8 re8, im8;
        #pragma unroll
        for (int e = 0; e < 8; ++e) {
            re8[e] = (short)f2bf(vr[e]);
            im8[e] = (short)f2bf(vi[e]);
        }
        *(short8*)&sm[OPR + t * 16] = re8;
        *(short8*)&sm[OPI + t * 16] = im8;
    }
    __syncthreads();   // B1: kl staged, Bs/Cs/P32/w32 ready

    if (t < 64) {   // taps F[m] = sum_j C[j+m] B[j] (+D at m=0); fixed-trip predicated
        const float* Bp = (const float*)&sm[OBS];
        const float* Cp = (const float*)&sm[OCS];
        float f = (t == 0) ? ssm_k_D[h] : 0.f;
        #pragma unroll 8
        for (int j = 0; j < 64; ++j) {
            float cv = Cp[(j + t) & 63];
            f = fmaf((j + t < 64) ? cv : 0.f, Bp[j], f);
        }
        ((float*)&sm[OF])[t] = f;
    }
    __syncthreads();   // B2: F ready

    {   // Afir[i][k] = F[64+i-k], rows stride 208B
        int i = t >> 4, ks = t & 15;
        if (ks < 12) {
            const float* Fp = (const float*)&sm[OF];
            short8 row;
            #pragma unroll
            for (int e = 0; e < 8; ++e) {
                int k = ks * 8 + e;
                int m = 64 + i - k;
                float v = (m >= 0 && m < 64) ? Fp[m] : 0.f;
                row[e] = (short)f2bf(v);
            }
            *(short8*)&sm[OAF + i * 208 + ks * 16] = row;
        }
    }
    __syncthreads();   // B3: Afir ready

    // ---- FIR via MFMA: wave wv -> row rl=wv>>1, jg in [4*(wv&1), +4) ----
    {
        short8 afr[3];
        #pragma unroll
        for (int ks = 0; ks < 3; ++ks)
            afr[ks] = *(const short8*)&sm[OAF + (lane & 15) * 208 + ks * 64 + (lane >> 4) * 16];
        const int rl = wv >> 1;
        const int jbase = (wv & 1) * 4;
        #pragma unroll
        for (int jj = 0; jj < 4; ++jj) {
            const int jg = jbase + jj;
            f32x4 d = (f32x4){0.f, 0.f, 0.f, 0.f};
            #pragma unroll
            for (int ks = 0; ks < 3; ++ks) {
                int o = rl * 4352 + (jg * 256 + (lane & 15) * 16 + ks * 32 + (lane >> 4) * 8) * 2;
                o ^= ((o >> 7) & 7) << 4;     // SWL
                short8 bfrag = *(const short8*)&sm[OKL + o];
                d = __builtin_amdgcn_mfma_f32_16x16x32_bf16(afr[ks], bfrag, d, 0, 0, 0);
            }
            unsigned pk0 = ((unsigned)f2bf(d[0])) | (((unsigned)f2bf(d[1])) << 16);
            unsigned pk1 = ((unsigned)f2bf(d[2])) | (((unsigned)f2bf(d[3])) << 16);
            int o2 = rl * 4096 + jg * 512 + (lane & 15) * 32 + (lane >> 4) * 8;
            o2 ^= ((o2 >> 9) & 7) << 4;       // SWK
            *(u32x2*)&sm[OKK + o2] = (u32x2){pk0, pk1};
        }
    }
    __syncthreads();   // B4: kk ready

    // ---- phase 2: contrib via MFMA + w32-Horner; wave wv owns mt = wv ----
    {
        const int mt = wv;
        short8 par = *(const short8*)&sm[OPR + (mt * 16 + (lane & 15)) * 64 + (lane >> 4) * 16];
        short8 pai = *(const short8*)&sm[OPI + (mt * 16 + (lane & 15)) * 64 + (lane >> 4) * 16];
        float w32r[4], w32i[4];
        #pragma unroll
        for (int rg = 0; rg < 4; ++rg) {
            int n = mt * 16 + (lane >> 4) * 4 + rg;
            float2 ww = *(const float2*)&sm[OW32 + n * 8];
            w32r[rg] = ww.x;
            w32i[rg] = ww.y;
        }
        f32x4 cr = (f32x4){0.f, 0.f, 0.f, 0.f};
        f32x4 ci_ = (f32x4){0.f, 0.f, 0.f, 0.f};
        const int colb = (lane & 15) >> 3;    // local b
        const int colr = lane & 7;            // chunk r
        #pragma unroll
        for (int g = 0; g < 8; ++g) {
            int o = colb * 4096 + colr * 512 + g * 64 + (lane >> 4) * 16;
            o ^= ((o >> 9) & 7) << 4;         // SWK
            short8 kf = *(const short8*)&sm[OKK + o];
            f32x4 sre = __builtin_amdgcn_mfma_f32_16x16x32_bf16(par, kf, (f32x4){0.f,0.f,0.f,0.f}, 0, 0, 0);
            f32x4 sim = __builtin_amdgcn_mfma_f32_16x16x32_bf16(pai, kf, (f32x4){0.f,0.f,0.f,0.f}, 0, 0, 0);
            #pragma unroll
            for (int rg = 0; rg < 4; ++rg) {
                float wr = w32r[rg], wi = w32i[rg];
                float ncr = fmaf(cr[rg], wr, fmaf(-ci_[rg], wi, sre[rg]));
                float nci = fmaf(cr[rg], wi, fmaf(ci_[rg], wr, sim[rg]));
                cr[rg] = ncr;
                ci_[rg] = nci;
            }
        }
        __syncthreads();   // B5: all kf reads done before ctb overlays kk
        // ctb: re at OKK[n*17+c], im at OKK+4352 (spills into dead Afir)
        #pragma unroll
        for (int rg = 0; rg < 4; ++rg) {
            int n = mt * 16 + (lane >> 4) * 4 + rg;
            int c = lane & 15;
            ((float*)&sm[OKK])[n * 17 + c] = cr[rg];
            ((float*)&sm[OKK])[1088 + n * 17 + c] = ci_[rg];
        }
    }
    __syncthreads();   // B6: ctb ready

    // ---- scan over 8 chunks + dB readout: threads t<128, n=t&63, bl=t>>6 ----
    if (t < 128) {
        const int n = t & 63, bl = t >> 6;
        const int b = bg * 2 + bl;
        float Are, Aim, lre, lim;
        get_disc(log_dt, log_A_real, A_imag, h, n, Are, Aim, lre, lim);
        float er = expf(lre), sn, cs;
        sincosf(lim, &sn, &cs);
        float wr = er * cs, wi = er * sn;
        float2 w32v = *(const float2*)&sm[OW32 + n * 8];
        float ar = w32v.x, ai = w32v.y;      // -> w^256 by 3 squarings
        #pragma unroll
        for (int s = 0; s < 3; ++s) {
            float nr = ar * ar - ai * ai;
            ai = 2.f * ar * ai;
            ar = nr;
        }
        float den = Are * Are + Aim * Aim;
        float wm1r = wr - 1.f, wm1i = wi;
        float tr_ = (wm1r * Are + wm1i * Aim) / den;
        float ti_ = (wm1i * Are - wm1r * Aim) / den;
        float br = B_re[h * 64 + n], bi = B_im[h * 64 + n];
        float dBr = br * tr_ - bi * ti_;
        float dBi = br * ti_ + bi * tr_;
        const float* cre = (const float*)&sm[OKK] + n * 17 + bl * 8;
        const float* cim = (const float*)&sm[OKK] + 1088 + n * 17 + bl * 8;
        float sr = 0.f, si_ = 0.f;
        #pragma unroll
        for (int r = 0; r < 8; ++r) {
            float nsr = fmaf(ar, sr, fmaf(-ai, si_, cre[r]));
            float nsi = fmaf(ar, si_, fmaf(ai, sr, cim[r]));
            sr = nsr; si_ = nsi;
            out[(((size_t)b * NREC + r) * DM + h) * 64 + n] = dBr * sr - dBi * si_;
        }
    }
}

extern "C" void kernel_launch(void* const* d_in, const int* in_sizes, int n_in,
                              void* d_out, int out_size, void* d_ws, size_t ws_size,
                              hipStream_t stream)
{
    const float* u       = (const float*)d_in[0];
    const float* W       = (const float*)d_in[1];
    const float* bias    = (const float*)d_in[2];
    const float* shift_B = (const float*)d_in[3];
    const float* shift_C = (const float*)d_in[4];
    const float* ssm_k_D = (const float*)d_in[5];
    const float* log_dt  = (const float*)d_in[6];
    const float* log_Ar  = (const float*)d_in[7];
    const float* A_imag  = (const float*)d_in[8];
    const float* B_re    = (const float*)d_in[9];
    const float* B_im    = (const float*)d_in[10];
    float* out = (float*)d_out;

    const int n_u = 8 * L_SEQ * DM;     // 16M elems
    const int n_w = DM * DM;            // 1M elems
    unsigned short* ub   = (unsigned short*)d_ws;            // [0, 32MB)
    unsigned short* klin = ub + (size_t)n_u;                 // [32MB, 64MB)
    unsigned short* Wb   = klin + (size_t)n_u;               // [64MB, 66MB)

    const bool prew = ws_size >= (size_t)66 * 1024 * 1024;

    if (prew) {
        cvt2_bf16<<<(n_u + n_w) / (256 * 8), 256, 0, stream>>>(u, ub, n_u, W, Wb, n_w);
        gemm_klin<true><<<dim3(1024), 256, 0, stream>>>(W, Wb, ub, bias, klin);
    } else {
        cvt2_bf16<<<n_u / (256 * 8), 256, 0, stream>>>(u, ub, n_u, W, Wb, 0);
        gemm_klin<false><<<dim3(1024), 256, 0, stream>>>(W, Wb, ub, bias, klin);
    }

    expand<<<dim3(DM, 4), 256, 0, stream>>>(klin, shift_B, shift_C, ssm_k_D, log_dt,
                                            log_Ar, A_imag, B_re, B_im, out);
}

// Round 6
// 87.526 us; speedup vs baseline: 7.6738x; 1.0076x over previous
//
#include <hip/hip_runtime.h>
#include <cstddef>
#include <cstdint>

#define L_SEQ 2048
#define DM    1024
#define NREC  8
#define BM 128
#define BN 128
#define BK 32
#define NT (DM / BK)

typedef __attribute__((ext_vector_type(8))) short short8;
typedef __attribute__((ext_vector_type(4))) float f32x4;
typedef __attribute__((ext_vector_type(2))) unsigned int u32x2;

__device__ inline unsigned short f2bf(float f) {
    unsigned u = __float_as_uint(f);
    unsigned r = (u + 0x7FFFu + ((u >> 16) & 1u)) >> 16;
    return (unsigned short)r;
}
__device__ inline float bf2f(unsigned short s) {
    return __uint_as_float(((unsigned)s) << 16);
}
__device__ inline void gload_lds16(const void* g, void* l) {
    __builtin_amdgcn_global_load_lds(
        (const __attribute__((address_space(1))) void*)g,
        (__attribute__((address_space(3))) void*)l, 16, 0, 0);
}

// ---------------- f32 -> bf16 for u (na elems) and optionally W (nb elems) ----
__global__ __launch_bounds__(256) void cvt2_bf16(
    const float* __restrict__ a, unsigned short* __restrict__ oa, int na,
    const float* __restrict__ b, unsigned short* __restrict__ ob, int nb)
{
    int i = (blockIdx.x * 256 + threadIdx.x) * 8;
    const float* src;
    unsigned short* dst;
    if (i < na) { src = a + i; dst = oa + i; }
    else {
        int j = i - na;
        if (j >= nb) return;
        src = b + j; dst = ob + j;
    }
    f32x4 v0 = *(const f32x4*)(src);
    f32x4 v1 = *(const f32x4*)(src + 4);
    short8 o;
    o[0] = (short)f2bf(v0[0]); o[1] = (short)f2bf(v0[1]);
    o[2] = (short)f2bf(v0[2]); o[3] = (short)f2bf(v0[3]);
    o[4] = (short)f2bf(v1[0]); o[5] = (short)f2bf(v1[1]);
    o[6] = (short)f2bf(v1[2]); o[7] = (short)f2bf(v1[3]);
    *(short8*)dst = o;
}

// ---------------- bf16 MFMA GEMM: klin[b][h][l] = sum_d W[h][d] u[b][l][d] + bias[h]
// LDS tile: 128 rows x 32 k bf16 = 64B/row. Pair-granule swizzle:
//   granule = 16B; pair p = row>>1 holds 8 granules (128B = all 32 banks);
//   logical g = (row&1)*4 + slot;  phys = g ^ (p&7).
// Fragment read (16 lanes, consecutive rows, fixed slot) hits each 4-bank
// group exactly 2x per quarter-wave -> theoretical-min 8cyc per b128.
// Staged via global_load_lds (linear dest); inverse perm folded into the
// per-lane GLOBAL source address (both-sides rule).
template<bool PREW>
__global__ __launch_bounds__(256, 2) void gemm_klin(
    const float* __restrict__ Wf, const unsigned short* __restrict__ Wb,
    const unsigned short* __restrict__ ub,
    const float* __restrict__ bias, unsigned short* __restrict__ klin)
{
    __shared__ unsigned short As[2][BM * BK];
    __shared__ unsigned short Bs[2][BM * BK];
    int wg = (int)blockIdx.x;
    wg = (wg & 7) * 128 + (wg >> 3);
    const int b  = wg >> 7;
    const int h0 = ((wg >> 4) & 7) * BM;
    const int l0 = (wg & 15) * BN;
    const int tid = threadIdx.x;
    const int lane = tid & 63, wv = tid >> 6;

    // staging source geometry (per lane): instruction j covers pairs
    // p = j*8 + l3, phys granule = l7 -> logical g = l7 ^ l3
    const int l3 = lane >> 3, l7 = lane & 7;
    const int g  = l7 ^ l3;
    const int rij  = l3 * 2 + (g >> 2);   // row within the 16-row group
    const int kcol = (g & 3) * 8;         // k element offset

    const int rA0 = 2 * wv * 16 + rij;    // rows for instr j=2wv, 2wv+1
    const unsigned short* gA0b = Wb + (size_t)(h0 + rA0) * DM + kcol;
    const unsigned short* gA1b = gA0b + 16 * DM;
    const unsigned short* gB0 = ub + ((size_t)(b * L_SEQ + l0 + rA0)) * DM + kcol;
    const unsigned short* gB1 = gB0 + 16 * DM;

    // fallback (!PREW) f32 A-load geometry: rows r0/r1, 32B per lane
    const int r0 = wv * 32 + (lane >> 2);
    const int r1 = r0 + 16;
    const int slotF = lane & 3;
    const float* gA0f = Wf + (size_t)(h0 + r0) * DM + slotF * 8;
    const float* gA1f = Wf + (size_t)(h0 + r1) * DM + slotF * 8;
    // fallback ds_write phys byte offsets
    const int w0off = (r0 >> 1) * 128 + ((((r0 & 1) << 2) + slotF) ^ ((r0 >> 1) & 7)) * 16;
    const int w1off = (r1 >> 1) * 128 + ((((r1 & 1) << 2) + slotF) ^ ((r1 >> 1) & 7)) * 16;

    const int wm = wv >> 1, wn = wv & 1;
    const int lr = lane & 15, lk = lane >> 4;
    // fragment read: per-lane constant byte offset within a 16-row group
    const int foff = (lr >> 1) * 128 + ((((lr & 1) << 2) + lk) ^ (lr >> 1)) * 16;

    f32x4 acc[4][4];
    #pragma unroll
    for (int m = 0; m < 4; ++m)
        #pragma unroll
        for (int n = 0; n < 4; ++n) acc[m][n] = (f32x4){0.f, 0.f, 0.f, 0.f};

    // prologue: stage tile 0
    gload_lds16(gB0, &Bs[0][(2 * wv) * 512]);
    gload_lds16(gB1, &Bs[0][(2 * wv + 1) * 512]);
    if constexpr (PREW) {
        gload_lds16(gA0b, &As[0][(2 * wv) * 512]);
        gload_lds16(gA1b, &As[0][(2 * wv + 1) * 512]);
    } else {
        f32x4 a0 = *(const f32x4*)(gA0f);
        f32x4 a1 = *(const f32x4*)(gA0f + 4);
        f32x4 a2 = *(const f32x4*)(gA1f);
        f32x4 a3 = *(const f32x4*)(gA1f + 4);
        short8 c0, c1;
        c0[0]=(short)f2bf(a0[0]); c0[1]=(short)f2bf(a0[1]); c0[2]=(short)f2bf(a0[2]); c0[3]=(short)f2bf(a0[3]);
        c0[4]=(short)f2bf(a1[0]); c0[5]=(short)f2bf(a1[1]); c0[6]=(short)f2bf(a1[2]); c0[7]=(short)f2bf(a1[3]);
        c1[0]=(short)f2bf(a2[0]); c1[1]=(short)f2bf(a2[1]); c1[2]=(short)f2bf(a2[2]); c1[3]=(short)f2bf(a2[3]);
        c1[4]=(short)f2bf(a3[0]); c1[5]=(short)f2bf(a3[1]); c1[6]=(short)f2bf(a3[2]); c1[7]=(short)f2bf(a3[3]);
        *(short8*)((char*)&As[0][0] + w0off) = c0;
        *(short8*)((char*)&As[0][0] + w1off) = c1;
    }

    for (int kt = 0; kt < NT; ++kt) {
        __syncthreads();   // buf[kt&1] staged (sync drains vmcnt+lgkmcnt)
        const int bf = kt & 1;
        const bool more = (kt + 1 < NT);
        f32x4 a0, a1, a2, a3;
        if (more) {
            const int ko = (kt + 1) * BK;
            gload_lds16(gB0 + ko, &Bs[bf ^ 1][(2 * wv) * 512]);
            gload_lds16(gB1 + ko, &Bs[bf ^ 1][(2 * wv + 1) * 512]);
            if constexpr (PREW) {
                gload_lds16(gA0b + ko, &As[bf ^ 1][(2 * wv) * 512]);
                gload_lds16(gA1b + ko, &As[bf ^ 1][(2 * wv + 1) * 512]);
            } else {
                a0 = *(const f32x4*)(gA0f + ko);
                a1 = *(const f32x4*)(gA0f + ko + 4);
                a2 = *(const f32x4*)(gA1f + ko);
                a3 = *(const f32x4*)(gA1f + ko + 4);
            }
        }
        short8 af[4], bfr[4];
        #pragma unroll
        for (int m = 0; m < 4; ++m) {
            const int rb = wm * 64 + m * 16;
            af[m] = *(const short8*)((const char*)&As[bf][0] + rb * 64 + foff);
        }
        #pragma unroll
        for (int n = 0; n < 4; ++n) {
            const int rb = wn * 64 + n * 16;
            bfr[n] = *(const short8*)((const char*)&Bs[bf][0] + rb * 64 + foff);
        }
        #pragma unroll
        for (int m = 0; m < 4; ++m)
            #pragma unroll
            for (int n = 0; n < 4; ++n)
                acc[m][n] = __builtin_amdgcn_mfma_f32_16x16x32_bf16(af[m], bfr[n], acc[m][n], 0, 0, 0);
        if constexpr (!PREW) {
            if (more) {
                short8 c0, c1;
                c0[0]=(short)f2bf(a0[0]); c0[1]=(short)f2bf(a0[1]); c0[2]=(short)f2bf(a0[2]); c0[3]=(short)f2bf(a0[3]);
                c0[4]=(short)f2bf(a1[0]); c0[5]=(short)f2bf(a1[1]); c0[6]=(short)f2bf(a1[2]); c0[7]=(short)f2bf(a1[3]);
                c1[0]=(short)f2bf(a2[0]); c1[1]=(short)f2bf(a2[1]); c1[2]=(short)f2bf(a2[2]); c1[3]=(short)f2bf(a2[3]);
                c1[4]=(short)f2bf(a3[0]); c1[5]=(short)f2bf(a3[1]); c1[6]=(short)f2bf(a3[2]); c1[7]=(short)f2bf(a3[3]);
                *(short8*)((char*)&As[bf ^ 1][0] + w0off) = c0;
                *(short8*)((char*)&As[bf ^ 1][0] + w1off) = c1;
            }
        }
    }

    // epilogue: D row=(lane>>4)*4+reg (h), col=lane&15 (l)
    #pragma unroll
    for (int m = 0; m < 4; ++m) {
        const int h = h0 + wm * 64 + m * 16 + lk * 4;
        #pragma unroll
        for (int n = 0; n < 4; ++n) {
            const int l = l0 + wn * 64 + n * 16 + lr;
            #pragma unroll
            for (int r = 0; r < 4; ++r) {
                float v = acc[m][n][r] + bias[h + r];
                klin[((size_t)b * DM + h + r) * L_SEQ + l] = f2bf(v);
            }
        }
    }
}

// ---------------- expand: one block per (h, b-pair); 29.7KB LDS (unchanged r5) ----
__device__ inline void get_disc(const float* __restrict__ log_dt,
                                const float* __restrict__ lar,
                                const float* __restrict__ aim, int h, int n,
                                float& Are, float& Aim, float& lre, float& lim)
{
    float dtv = expf(log_dt[h]);
    Are = -expf(lar[h * 64 + n]);
    Aim = aim[h * 64 + n];
    lre = dtv * Are;
    lim = dtv * Aim;
}

__global__ __launch_bounds__(256, 5) void expand(
    const unsigned short* __restrict__ klin,
    const float* __restrict__ shift_B, const float* __restrict__ shift_C,
    const float* __restrict__ ssm_k_D, const float* __restrict__ log_dt,
    const float* __restrict__ log_A_real, const float* __restrict__ A_imag,
    const float* __restrict__ B_re, const float* __restrict__ B_im,
    float* __restrict__ out)
{
    __shared__ __align__(16) char sm[29696];
    constexpr int OKL = 0;
    constexpr int OKK = 8704;
    constexpr int OAF = 16896;
    constexpr int OPR = 20224;
    constexpr int OPI = 24320;
    constexpr int OF  = 28416;
    constexpr int OBS = 28672;
    constexpr int OCS = 28928;
    constexpr int OW32 = 29184;

    const int h  = blockIdx.x;
    const int bg = blockIdx.y;      // b-pair index 0..3
    const int t = threadIdx.x;
    const int lane = t & 63, wv = t >> 6;

    if (t < 32) {
        int rl = t >> 4, reg = (t >> 3) & 1, idx = t & 7;
        *(f32x4*)&sm[OKL + rl * 4352 + reg * 4224 + idx * 16] = (f32x4){0.f, 0.f, 0.f, 0.f};
    }
    {
        const int rl = wv >> 1, hf = wv & 1;
        const int b = bg * 2 + rl;
        const char* krow = (const char*)(klin + ((size_t)b * DM + h) * L_SEQ);
        const int s = (2 * rl + 1 + (lane >> 3)) & 7;
        const int so = hf * 2048 + (lane >> 3) * 128 + ((lane ^ s) & 7) * 16;
        gload_lds16(krow + so,        &sm[OKL + rl * 4352 + 128 + hf * 2048]);
        gload_lds16(krow + so + 1024, &sm[OKL + rl * 4352 + 128 + hf * 2048 + 1024]);
    }
    if (t < 64) {
        ((float*)&sm[OBS])[t] = shift_B[h * 64 + t];
        ((float*)&sm[OCS])[t] = shift_C[h * 64 + t];
        float Are, Aim, lre, lim;
        get_disc(log_dt, log_A_real, A_imag, h, t, Are, Aim, lre, lim);
        float er = expf(32.f * lre);
        float sn, cs; sincosf(32.f * lim, &sn, &cs);
        ((float*)&sm[OW32])[t * 2]     = er * cs;
        ((float*)&sm[OW32])[t * 2 + 1] = er * sn;
    }
    {   // P32[n][j] = w_n^{31-j}: n = t>>2, j-seg s4 = t&3
        int n = t >> 2, s4 = t & 3;
        float Are, Aim, lre, lim;
        get_disc(log_dt, log_A_real, A_imag, h, n, Are, Aim, lre, lim);
        float erw = expf(lre), snw, csw;
        sincosf(lim, &snw, &csw);
        float wr = erw * csw, wi = erw * snw;
        float e0 = (float)(24 - 8 * s4);
        float mag = expf(e0 * lre);
        float sn0, cs0; sincosf(e0 * lim, &sn0, &cs0);
        float pr = mag * cs0, pi = mag * sn0;
        float vr[8], vi[8];
        vr[7] = pr; vi[7] = pi;
        #pragma unroll
        for (int k = 6; k >= 0; --k) {
            float nr = pr * wr - pi * wi;
            pi = fmaf(pr, wi, pi * wr);
            pr = nr;
            vr[k] = pr; vi[k] = pi;
        }
        short8 re8, im8;
        #pragma unroll
        for (int e = 0; e < 8; ++e) {
            re8[e] = (short)f2bf(vr[e]);
            im8[e] = (short)f2bf(vi[e]);
        }
        *(short8*)&sm[OPR + t * 16] = re8;
        *(short8*)&sm[OPI + t * 16] = im8;
    }
    __syncthreads();   // B1

    if (t < 64) {
        const float* Bp = (const float*)&sm[OBS];
        const float* Cp = (const float*)&sm[OCS];
        float f = (t == 0) ? ssm_k_D[h] : 0.f;
        #pragma unroll 8
        for (int j = 0; j < 64; ++j) {
            float cv = Cp[(j + t) & 63];
            f = fmaf((j + t < 64) ? cv : 0.f, Bp[j], f);
        }
        ((float*)&sm[OF])[t] = f;
    }
    __syncthreads();   // B2

    {
        int i = t >> 4, ks = t & 15;
        if (ks < 12) {
            const float* Fp = (const float*)&sm[OF];
            short8 row;
            #pragma unroll
            for (int e = 0; e < 8; ++e) {
                int k = ks * 8 + e;
                int m = 64 + i - k;
                float v = (m >= 0 && m < 64) ? Fp[m] : 0.f;
                row[e] = (short)f2bf(v);
            }
            *(short8*)&sm[OAF + i * 208 + ks * 16] = row;
        }
    }
    __syncthreads();   // B3

    {
        short8 afr[3];
        #pragma unroll
        for (int ks = 0; ks < 3; ++ks)
            afr[ks] = *(const short8*)&sm[OAF + (lane & 15) * 208 + ks * 64 + (lane >> 4) * 16];
        const int rl = wv >> 1;
        const int jbase = (wv & 1) * 4;
        #pragma unroll
        for (int jj = 0; jj < 4; ++jj) {
            const int jg = jbase + jj;
            f32x4 d = (f32x4){0.f, 0.f, 0.f, 0.f};
            #pragma unroll
            for (int ks = 0; ks < 3; ++ks) {
                int o = rl * 4352 + (jg * 256 + (lane & 15) * 16 + ks * 32 + (lane >> 4) * 8) * 2;
                o ^= ((o >> 7) & 7) << 4;     // SWL
                short8 bfrag = *(const short8*)&sm[OKL + o];
                d = __builtin_amdgcn_mfma_f32_16x16x32_bf16(afr[ks], bfrag, d, 0, 0, 0);
            }
            unsigned pk0 = ((unsigned)f2bf(d[0])) | (((unsigned)f2bf(d[1])) << 16);
            unsigned pk1 = ((unsigned)f2bf(d[2])) | (((unsigned)f2bf(d[3])) << 16);
            int o2 = rl * 4096 + jg * 512 + (lane & 15) * 32 + (lane >> 4) * 8;
            o2 ^= ((o2 >> 9) & 7) << 4;       // SWK
            *(u32x2*)&sm[OKK + o2] = (u32x2){pk0, pk1};
        }
    }
    __syncthreads();   // B4

    {
        const int mt = wv;
        short8 par = *(const short8*)&sm[OPR + (mt * 16 + (lane & 15)) * 64 + (lane >> 4) * 16];
        short8 pai = *(const short8*)&sm[OPI + (mt * 16 + (lane & 15)) * 64 + (lane >> 4) * 16];
        float w32r[4], w32i[4];
        #pragma unroll
        for (int rg = 0; rg < 4; ++rg) {
            int n = mt * 16 + (lane >> 4) * 4 + rg;
            float2 ww = *(const float2*)&sm[OW32 + n * 8];
            w32r[rg] = ww.x;
            w32i[rg] = ww.y;
        }
        f32x4 cr = (f32x4){0.f, 0.f, 0.f, 0.f};
        f32x4 ci_ = (f32x4){0.f, 0.f, 0.f, 0.f};
        const int colb = (lane & 15) >> 3;
        const int colr = lane & 7;
        #pragma unroll
        for (int g2 = 0; g2 < 8; ++g2) {
            int o = colb * 4096 + colr * 512 + g2 * 64 + (lane >> 4) * 16;
            o ^= ((o >> 9) & 7) << 4;         // SWK
            short8 kf = *(const short8*)&sm[OKK + o];
            f32x4 sre = __builtin_amdgcn_mfma_f32_16x16x32_bf16(par, kf, (f32x4){0.f,0.f,0.f,0.f}, 0, 0, 0);
            f32x4 sim = __builtin_amdgcn_mfma_f32_16x16x32_bf16(pai, kf, (f32x4){0.f,0.f,0.f,0.f}, 0, 0, 0);
            #pragma unroll
            for (int rg = 0; rg < 4; ++rg) {
                float wr = w32r[rg], wi = w32i[rg];
                float ncr = fmaf(cr[rg], wr, fmaf(-ci_[rg], wi, sre[rg]));
                float nci = fmaf(cr[rg], wi, fmaf(ci_[rg], wr, sim[rg]));
                cr[rg] = ncr;
                ci_[rg] = nci;
            }
        }
        __syncthreads();   // B5: all kf reads done before ctb overlays kk
        #pragma unroll
        for (int rg = 0; rg < 4; ++rg) {
            int n = mt * 16 + (lane >> 4) * 4 + rg;
            int c = lane & 15;
            ((float*)&sm[OKK])[n * 17 + c] = cr[rg];
            ((float*)&sm[OKK])[1088 + n * 17 + c] = ci_[rg];
        }
    }
    __syncthreads();   // B6

    if (t < 128) {
        const int n = t & 63, bl = t >> 6;
        const int b = bg * 2 + bl;
        float Are, Aim, lre, lim;
        get_disc(log_dt, log_A_real, A_imag, h, n, Are, Aim, lre, lim);
        float er = expf(lre), sn, cs;
        sincosf(lim, &sn, &cs);
        float wr = er * cs, wi = er * sn;
        float2 w32v = *(const float2*)&sm[OW32 + n * 8];
        float ar = w32v.x, ai = w32v.y;
        #pragma unroll
        for (int s = 0; s < 3; ++s) {
            float nr = ar * ar - ai * ai;
            ai = 2.f * ar * ai;
            ar = nr;
        }
        float den = Are * Are + Aim * Aim;
        float wm1r = wr - 1.f, wm1i = wi;
        float tr_ = (wm1r * Are + wm1i * Aim) / den;
        float ti_ = (wm1i * Are - wm1r * Aim) / den;
        float br = B_re[h * 64 + n], bi = B_im[h * 64 + n];
        float dBr = br * tr_ - bi * ti_;
        float dBi = br * ti_ + bi * tr_;
        const float* cre = (const float*)&sm[OKK] + n * 17 + bl * 8;
        const float* cim = (const float*)&sm[OKK] + 1088 + n * 17 + bl * 8;
        float sr = 0.f, si_ = 0.f;
        #pragma unroll
        for (int r = 0; r < 8; ++r) {
            float nsr = fmaf(ar, sr, fmaf(-ai, si_, cre[r]));
            float nsi = fmaf(ar, si_, fmaf(ai, sr, cim[r]));
            sr = nsr; si_ = nsi;
            out[(((size_t)b * NREC + r) * DM + h) * 64 + n] = dBr * sr - dBi * si_;
        }
    }
}

extern "C" void kernel_launch(void* const* d_in, const int* in_sizes, int n_in,
                              void* d_out, int out_size, void* d_ws, size_t ws_size,
                              hipStream_t stream)
{
    const float* u       = (const float*)d_in[0];
    const float* W       = (const float*)d_in[1];
    const float* bias    = (const float*)d_in[2];
    const float* shift_B = (const float*)d_in[3];
    const float* shift_C = (const float*)d_in[4];
    const float* ssm_k_D = (const float*)d_in[5];
    const float* log_dt  = (const float*)d_in[6];
    const float* log_Ar  = (const float*)d_in[7];
    const float* A_imag  = (const float*)d_in[8];
    const float* B_re    = (const float*)d_in[9];
    const float* B_im    = (const float*)d_in[10];
    float* out = (float*)d_out;

    const int n_u = 8 * L_SEQ * DM;     // 16M elems
    const int n_w = DM * DM;            // 1M elems
    unsigned short* ub   = (unsigned short*)d_ws;            // [0, 32MB)
    unsigned short* klin = ub + (size_t)n_u;                 // [32MB, 64MB)
    unsigned short* Wb   = klin + (size_t)n_u;               // [64MB, 66MB)

    const bool prew = ws_size >= (size_t)66 * 1024 * 1024;

    if (prew) {
        cvt2_bf16<<<(n_u + n_w) / (256 * 8), 256, 0, stream>>>(u, ub, n_u, W, Wb, n_w);
        gemm_klin<true><<<dim3(1024), 256, 0, stream>>>(W, Wb, ub, bias, klin);
    } else {
        cvt2_bf16<<<n_u / (256 * 8), 256, 0, stream>>>(u, ub, n_u, W, Wb, 0);
        gemm_klin<false><<<dim3(1024), 256, 0, stream>>>(W, Wb, ub, bias, klin);
    }

    expand<<<dim3(DM, 4), 256, 0, stream>>>(klin, shift_B, shift_C, ssm_k_D, log_dt,
                                            log_Ar, A_imag, B_re, B_im, out);
}

// Round 7
// 81.882 us; speedup vs baseline: 8.2027x; 1.0689x over previous
//
#include <hip/hip_runtime.h>
#include <cstddef>
#include <cstdint>

#define L_SEQ 2048
#define DM    1024
#define NREC  8
#define BM 128
#define BN 128
#define BK 32
#define NT (DM / BK)

typedef __attribute__((ext_vector_type(8))) short short8;
typedef __attribute__((ext_vector_type(4))) float f32x4;
typedef __attribute__((ext_vector_type(2))) unsigned int u32x2;

__device__ inline unsigned short f2bf(float f) {
    unsigned u = __float_as_uint(f);
    unsigned r = (u + 0x7FFFu + ((u >> 16) & 1u)) >> 16;
    return (unsigned short)r;
}
__device__ inline float bf2f(unsigned short s) {
    return __uint_as_float(((unsigned)s) << 16);
}
__device__ inline void gload_lds16(const void* g, void* l) {
    __builtin_amdgcn_global_load_lds(
        (const __attribute__((address_space(1))) void*)g,
        (__attribute__((address_space(3))) void*)l, 16, 0, 0);
}

// ---------------- f32 -> bf16 for u (na elems) and optionally W (nb elems) ----
__global__ __launch_bounds__(256) void cvt2_bf16(
    const float* __restrict__ a, unsigned short* __restrict__ oa, int na,
    const float* __restrict__ b, unsigned short* __restrict__ ob, int nb)
{
    int i = (blockIdx.x * 256 + threadIdx.x) * 8;
    const float* src;
    unsigned short* dst;
    if (i < na) { src = a + i; dst = oa + i; }
    else {
        int j = i - na;
        if (j >= nb) return;
        src = b + j; dst = ob + j;
    }
    f32x4 v0 = *(const f32x4*)(src);
    f32x4 v1 = *(const f32x4*)(src + 4);
    short8 o;
    o[0] = (short)f2bf(v0[0]); o[1] = (short)f2bf(v0[1]);
    o[2] = (short)f2bf(v0[2]); o[3] = (short)f2bf(v0[3]);
    o[4] = (short)f2bf(v1[0]); o[5] = (short)f2bf(v1[1]);
    o[6] = (short)f2bf(v1[2]); o[7] = (short)f2bf(v1[3]);
    *(short8*)dst = o;
}

// ================= 256x256 counted-vmcnt GEMM (T3+T4+T5) =================
// klin[b][h][l] = sum_d W[h][d] u[b][l][d] + bias[h]
// 8 waves (2M x 4N), BK=32, 4-deep LDS ring (128 KB), prefetch distance 3.
// Pipeline invariant: tile t+3 staged during tile t into buf[(t+3)&3], which
// was freed at the (t-1 -> t) barrier. At the boundary after tile t, loads
// newer than tile t+1's = 4*[(t+2<32)+(t+3<32)] -> vmcnt(8)/4/0; never a
// full drain in steady state. One barrier per K-tile.
// Swizzle (proven 0-conflict in r6): pair p=row>>1 holds 8 granules (128B);
// logical g = (row&1)*4 + slot; phys = g ^ (p&7); inverse folded into the
// per-lane GLOBAL source address (linear gload_lds dest).
__global__ __launch_bounds__(512, 2) void gemm_klin8(
    const unsigned short* __restrict__ Wb,
    const unsigned short* __restrict__ ub,
    const float* __restrict__ bias, unsigned short* __restrict__ klin)
{
    __shared__ unsigned short As[4][256 * 32];   // 4 x 16 KB
    __shared__ unsigned short Bs[4][256 * 32];   // 4 x 16 KB

    // XCD-contiguous: XCD x gets wg in [32x,32x+32) = one whole batch;
    // 4 consecutive wgs share one u l-panel (L2 reuse).
    int wg = (int)blockIdx.x;
    wg = (wg & 7) * 32 + (wg >> 3);
    const int b  = wg >> 5;
    const int l0 = ((wg >> 2) & 7) * 256;
    const int h0 = (wg & 3) * 256;
    const int tid = (int)threadIdx.x;
    const int lane = tid & 63, wv = tid >> 6;

    // staging source geometry: instr slot j covers pairs p = j*64 + wv*8 + l3;
    // lane writes phys granule l7 -> logical g = l7 ^ l3
    const int l3 = lane >> 3, l7 = lane & 7;
    const int gsw  = l7 ^ l3;
    const int rij  = l3 * 2 + (gsw >> 2);
    const int kcol = (gsw & 3) * 8;
    const int rA0  = wv * 16 + rij;

    const unsigned short* gA0 = Wb + (size_t)(h0 + rA0) * DM + kcol;
    const unsigned short* gA1 = gA0 + (size_t)128 * DM;
    const unsigned short* gB0 = ub + ((size_t)b * L_SEQ + l0 + rA0) * DM + kcol;
    const unsigned short* gB1 = gB0 + (size_t)128 * DM;
    const int dst0 = (wv * 8) * 128;        // byte offset, instr slot 0
    const int dst1 = (64 + wv * 8) * 128;   // instr slot 1

    const int wm = wv >> 2, wn = wv & 3;
    const int lr = lane & 15, lk = lane >> 4;
    const int foff = (lr >> 1) * 128 + ((((lr & 1) << 2) + lk) ^ (lr >> 1)) * 16;

    f32x4 acc[8][4];
    #pragma unroll
    for (int mf = 0; mf < 8; ++mf)
        #pragma unroll
        for (int nf = 0; nf < 4; ++nf) acc[mf][nf] = (f32x4){0.f, 0.f, 0.f, 0.f};

#define STG_A(T, BUF) do { const int ko_ = (T) * 32; \
    gload_lds16(gA0 + ko_, (char*)&As[BUF][0] + dst0); \
    gload_lds16(gA1 + ko_, (char*)&As[BUF][0] + dst1); } while (0)
#define STG_B(T, BUF) do { const int ko_ = (T) * 32; \
    gload_lds16(gB0 + ko_, (char*)&Bs[BUF][0] + dst0); \
    gload_lds16(gB1 + ko_, (char*)&Bs[BUF][0] + dst1); } while (0)

    // prologue: stage tiles 0,1,2 (12 loads); wait tile 0 (8 newer remain)
    STG_A(0, 0); STG_B(0, 0);
    STG_A(1, 1); STG_B(1, 1);
    STG_A(2, 2); STG_B(2, 2);
    asm volatile("s_waitcnt vmcnt(8)" ::: "memory");
    __builtin_amdgcn_s_barrier();
    asm volatile("" ::: "memory");

    #pragma unroll 1
    for (int t = 0; t < 32; ++t) {
        const int cur = t & 3, st = (t + 3) & 3;
        const char* Ab = (const char*)&As[cur][0];
        const char* Bb = (const char*)&Bs[cur][0];
        short8 af[4], bfr[4];
        // ---- phase 0: B frags + A mf0-3, stage A(t+3), 16 MFMA ----
        #pragma unroll
        for (int nf = 0; nf < 4; ++nf)
            bfr[nf] = *(const short8*)(Bb + (wn * 64 + nf * 16) * 64 + foff);
        #pragma unroll
        for (int mf = 0; mf < 4; ++mf)
            af[mf] = *(const short8*)(Ab + (wm * 128 + mf * 16) * 64 + foff);
        if (t + 3 < 32) STG_A(t + 3, st);
        __builtin_amdgcn_s_setprio(1);
        #pragma unroll
        for (int mf = 0; mf < 4; ++mf)
            #pragma unroll
            for (int nf = 0; nf < 4; ++nf)
                acc[mf][nf] = __builtin_amdgcn_mfma_f32_16x16x32_bf16(af[mf], bfr[nf], acc[mf][nf], 0, 0, 0);
        __builtin_amdgcn_s_setprio(0);
        // ---- phase 1: A mf4-7 (reuse B frags), stage B(t+3), 16 MFMA ----
        #pragma unroll
        for (int mf = 0; mf < 4; ++mf)
            af[mf] = *(const short8*)(Ab + (wm * 128 + (mf + 4) * 16) * 64 + foff);
        if (t + 3 < 32) STG_B(t + 3, st);
        __builtin_amdgcn_s_setprio(1);
        #pragma unroll
        for (int mf = 0; mf < 4; ++mf)
            #pragma unroll
            for (int nf = 0; nf < 4; ++nf)
                acc[mf + 4][nf] = __builtin_amdgcn_mfma_f32_16x16x32_bf16(af[mf], bfr[nf], acc[mf + 4][nf], 0, 0, 0);
        __builtin_amdgcn_s_setprio(0);
        // ---- boundary: counted wait (tile t+1 landed), barrier ----
        if (t <= 28)      asm volatile("s_waitcnt vmcnt(8)" ::: "memory");
        else if (t == 29) asm volatile("s_waitcnt vmcnt(4)" ::: "memory");
        else              asm volatile("s_waitcnt vmcnt(0)" ::: "memory");
        __builtin_amdgcn_s_barrier();
        asm volatile("" ::: "memory");
        __builtin_amdgcn_sched_barrier(0);
    }
#undef STG_A
#undef STG_B

    // epilogue: D row=(lane>>4)*4+reg (h), col=lane&15 (l)
    #pragma unroll
    for (int mf = 0; mf < 8; ++mf) {
        const int h = h0 + wm * 128 + mf * 16 + lk * 4;
        #pragma unroll
        for (int nf = 0; nf < 4; ++nf) {
            const int l = l0 + wn * 64 + nf * 16 + lr;
            #pragma unroll
            for (int r = 0; r < 4; ++r) {
                float v = acc[mf][nf][r] + bias[h + r];
                klin[((size_t)b * DM + h + r) * L_SEQ + l] = f2bf(v);
            }
        }
    }
}

// ---------------- fallback 128x128 2-phase GEMM (in-kernel W conversion) ----
__global__ __launch_bounds__(256, 2) void gemm_klin_fb(
    const float* __restrict__ Wf,
    const unsigned short* __restrict__ ub,
    const float* __restrict__ bias, unsigned short* __restrict__ klin)
{
    __shared__ unsigned short As[2][BM * BK];
    __shared__ unsigned short Bs[2][BM * BK];
    int wg = (int)blockIdx.x;
    wg = (wg & 7) * 128 + (wg >> 3);
    const int b  = wg >> 7;
    const int h0 = ((wg >> 4) & 7) * BM;
    const int l0 = (wg & 15) * BN;
    const int tid = threadIdx.x;
    const int lane = tid & 63, wv = tid >> 6;

    const int l3 = lane >> 3, l7 = lane & 7;
    const int g  = l7 ^ l3;
    const int rij  = l3 * 2 + (g >> 2);
    const int kcol = (g & 3) * 8;
    const int rA0 = 2 * wv * 16 + rij;
    const unsigned short* gB0 = ub + ((size_t)(b * L_SEQ + l0 + rA0)) * DM + kcol;
    const unsigned short* gB1 = gB0 + 16 * DM;

    const int r0 = wv * 32 + (lane >> 2);
    const int r1 = r0 + 16;
    const int slotF = lane & 3;
    const float* gA0f = Wf + (size_t)(h0 + r0) * DM + slotF * 8;
    const float* gA1f = Wf + (size_t)(h0 + r1) * DM + slotF * 8;
    const int w0off = (r0 >> 1) * 128 + ((((r0 & 1) << 2) + slotF) ^ ((r0 >> 1) & 7)) * 16;
    const int w1off = (r1 >> 1) * 128 + ((((r1 & 1) << 2) + slotF) ^ ((r1 >> 1) & 7)) * 16;

    const int wm = wv >> 1, wn = wv & 1;
    const int lr = lane & 15, lk = lane >> 4;
    const int foff = (lr >> 1) * 128 + ((((lr & 1) << 2) + lk) ^ (lr >> 1)) * 16;

    f32x4 acc[4][4];
    #pragma unroll
    for (int m = 0; m < 4; ++m)
        #pragma unroll
        for (int n = 0; n < 4; ++n) acc[m][n] = (f32x4){0.f, 0.f, 0.f, 0.f};

    gload_lds16(gB0, &Bs[0][(2 * wv) * 512]);
    gload_lds16(gB1, &Bs[0][(2 * wv + 1) * 512]);
    {
        f32x4 a0 = *(const f32x4*)(gA0f);
        f32x4 a1 = *(const f32x4*)(gA0f + 4);
        f32x4 a2 = *(const f32x4*)(gA1f);
        f32x4 a3 = *(const f32x4*)(gA1f + 4);
        short8 c0, c1;
        c0[0]=(short)f2bf(a0[0]); c0[1]=(short)f2bf(a0[1]); c0[2]=(short)f2bf(a0[2]); c0[3]=(short)f2bf(a0[3]);
        c0[4]=(short)f2bf(a1[0]); c0[5]=(short)f2bf(a1[1]); c0[6]=(short)f2bf(a1[2]); c0[7]=(short)f2bf(a1[3]);
        c1[0]=(short)f2bf(a2[0]); c1[1]=(short)f2bf(a2[1]); c1[2]=(short)f2bf(a2[2]); c1[3]=(short)f2bf(a2[3]);
        c1[4]=(short)f2bf(a3[0]); c1[5]=(short)f2bf(a3[1]); c1[6]=(short)f2bf(a3[2]); c1[7]=(short)f2bf(a3[3]);
        *(short8*)((char*)&As[0][0] + w0off) = c0;
        *(short8*)((char*)&As[0][0] + w1off) = c1;
    }

    for (int kt = 0; kt < NT; ++kt) {
        __syncthreads();
        const int bf = kt & 1;
        const bool more = (kt + 1 < NT);
        f32x4 a0, a1, a2, a3;
        if (more) {
            const int ko = (kt + 1) * BK;
            gload_lds16(gB0 + ko, &Bs[bf ^ 1][(2 * wv) * 512]);
            gload_lds16(gB1 + ko, &Bs[bf ^ 1][(2 * wv + 1) * 512]);
            a0 = *(const f32x4*)(gA0f + ko);
            a1 = *(const f32x4*)(gA0f + ko + 4);
            a2 = *(const f32x4*)(gA1f + ko);
            a3 = *(const f32x4*)(gA1f + ko + 4);
        }
        short8 af[4], bfr[4];
        #pragma unroll
        for (int m = 0; m < 4; ++m) {
            const int rb = wm * 64 + m * 16;
            af[m] = *(const short8*)((const char*)&As[bf][0] + rb * 64 + foff);
        }
        #pragma unroll
        for (int n = 0; n < 4; ++n) {
            const int rb = wn * 64 + n * 16;
            bfr[n] = *(const short8*)((const char*)&Bs[bf][0] + rb * 64 + foff);
        }
        #pragma unroll
        for (int m = 0; m < 4; ++m)
            #pragma unroll
            for (int n = 0; n < 4; ++n)
                acc[m][n] = __builtin_amdgcn_mfma_f32_16x16x32_bf16(af[m], bfr[n], acc[m][n], 0, 0, 0);
        if (more) {
            short8 c0, c1;
            c0[0]=(short)f2bf(a0[0]); c0[1]=(short)f2bf(a0[1]); c0[2]=(short)f2bf(a0[2]); c0[3]=(short)f2bf(a0[3]);
            c0[4]=(short)f2bf(a1[0]); c0[5]=(short)f2bf(a1[1]); c0[6]=(short)f2bf(a1[2]); c0[7]=(short)f2bf(a1[3]);
            c1[0]=(short)f2bf(a2[0]); c1[1]=(short)f2bf(a2[1]); c1[2]=(short)f2bf(a2[2]); c1[3]=(short)f2bf(a2[3]);
            c1[4]=(short)f2bf(a3[0]); c1[5]=(short)f2bf(a3[1]); c1[6]=(short)f2bf(a3[2]); c1[7]=(short)f2bf(a3[3]);
            *(short8*)((char*)&As[bf ^ 1][0] + w0off) = c0;
            *(short8*)((char*)&As[bf ^ 1][0] + w1off) = c1;
        }
    }

    #pragma unroll
    for (int m = 0; m < 4; ++m) {
        const int h = h0 + wm * 64 + m * 16 + lk * 4;
        #pragma unroll
        for (int n = 0; n < 4; ++n) {
            const int l = l0 + wn * 64 + n * 16 + lr;
            #pragma unroll
            for (int r = 0; r < 4; ++r) {
                float v = acc[m][n][r] + bias[h + r];
                klin[((size_t)b * DM + h + r) * L_SEQ + l] = f2bf(v);
            }
        }
    }
}

// ---------------- expand: one block per (h, b-pair); 29.7KB LDS (unchanged) ----
__device__ inline void get_disc(const float* __restrict__ log_dt,
                                const float* __restrict__ lar,
                                const float* __restrict__ aim, int h, int n,
                                float& Are, float& Aim, float& lre, float& lim)
{
    float dtv = expf(log_dt[h]);
    Are = -expf(lar[h * 64 + n]);
    Aim = aim[h * 64 + n];
    lre = dtv * Are;
    lim = dtv * Aim;
}

__global__ __launch_bounds__(256, 5) void expand(
    const unsigned short* __restrict__ klin,
    const float* __restrict__ shift_B, const float* __restrict__ shift_C,
    const float* __restrict__ ssm_k_D, const float* __restrict__ log_dt,
    const float* __restrict__ log_A_real, const float* __restrict__ A_imag,
    const float* __restrict__ B_re, const float* __restrict__ B_im,
    float* __restrict__ out)
{
    __shared__ __align__(16) char sm[29696];
    constexpr int OKL = 0;
    constexpr int OKK = 8704;
    constexpr int OAF = 16896;
    constexpr int OPR = 20224;
    constexpr int OPI = 24320;
    constexpr int OF  = 28416;
    constexpr int OBS = 28672;
    constexpr int OCS = 28928;
    constexpr int OW32 = 29184;

    const int h  = blockIdx.x;
    const int bg = blockIdx.y;
    const int t = threadIdx.x;
    const int lane = t & 63, wv = t >> 6;

    if (t < 32) {
        int rl = t >> 4, reg = (t >> 3) & 1, idx = t & 7;
        *(f32x4*)&sm[OKL + rl * 4352 + reg * 4224 + idx * 16] = (f32x4){0.f, 0.f, 0.f, 0.f};
    }
    {
        const int rl = wv >> 1, hf = wv & 1;
        const int b = bg * 2 + rl;
        const char* krow = (const char*)(klin + ((size_t)b * DM + h) * L_SEQ);
        const int s = (2 * rl + 1 + (lane >> 3)) & 7;
        const int so = hf * 2048 + (lane >> 3) * 128 + ((lane ^ s) & 7) * 16;
        gload_lds16(krow + so,        &sm[OKL + rl * 4352 + 128 + hf * 2048]);
        gload_lds16(krow + so + 1024, &sm[OKL + rl * 4352 + 128 + hf * 2048 + 1024]);
    }
    if (t < 64) {
        ((float*)&sm[OBS])[t] = shift_B[h * 64 + t];
        ((float*)&sm[OCS])[t] = shift_C[h * 64 + t];
        float Are, Aim, lre, lim;
        get_disc(log_dt, log_A_real, A_imag, h, t, Are, Aim, lre, lim);
        float er = expf(32.f * lre);
        float sn, cs; sincosf(32.f * lim, &sn, &cs);
        ((float*)&sm[OW32])[t * 2]     = er * cs;
        ((float*)&sm[OW32])[t * 2 + 1] = er * sn;
    }
    {
        int n = t >> 2, s4 = t & 3;
        float Are, Aim, lre, lim;
        get_disc(log_dt, log_A_real, A_imag, h, n, Are, Aim, lre, lim);
        float erw = expf(lre), snw, csw;
        sincosf(lim, &snw, &csw);
        float wr = erw * csw, wi = erw * snw;
        float e0 = (float)(24 - 8 * s4);
        float mag = expf(e0 * lre);
        float sn0, cs0; sincosf(e0 * lim, &sn0, &cs0);
        float pr = mag * cs0, pi = mag * sn0;
        float vr[8], vi[8];
        vr[7] = pr; vi[7] = pi;
        #pragma unroll
        for (int k = 6; k >= 0; --k) {
            float nr = pr * wr - pi * wi;
            pi = fmaf(pr, wi, pi * wr);
            pr = nr;
            vr[k] = pr; vi[k] = pi;
        }
        short8 re8, im8;
        #pragma unroll
        for (int e = 0; e < 8; ++e) {
            re8[e] = (short)f2bf(vr[e]);
            im8[e] = (short)f2bf(vi[e]);
        }
        *(short8*)&sm[OPR + t * 16] = re8;
        *(short8*)&sm[OPI + t * 16] = im8;
    }
    __syncthreads();   // B1

    if (t < 64) {
        const float* Bp = (const float*)&sm[OBS];
        const float* Cp = (const float*)&sm[OCS];
        float f = (t == 0) ? ssm_k_D[h] : 0.f;
        #pragma unroll 8
        for (int j = 0; j < 64; ++j) {
            float cv = Cp[(j + t) & 63];
            f = fmaf((j + t < 64) ? cv : 0.f, Bp[j], f);
        }
        ((float*)&sm[OF])[t] = f;
    }
    __syncthreads();   // B2

    {
        int i = t >> 4, ks = t & 15;
        if (ks < 12) {
            const float* Fp = (const float*)&sm[OF];
            short8 row;
            #pragma unroll
            for (int e = 0; e < 8; ++e) {
                int k = ks * 8 + e;
                int m = 64 + i - k;
                float v = (m >= 0 && m < 64) ? Fp[m] : 0.f;
                row[e] = (short)f2bf(v);
            }
            *(short8*)&sm[OAF + i * 208 + ks * 16] = row;
        }
    }
    __syncthreads();   // B3

    {
        short8 afr[3];
        #pragma unroll
        for (int ks = 0; ks < 3; ++ks)
            afr[ks] = *(const short8*)&sm[OAF + (lane & 15) * 208 + ks * 64 + (lane >> 4) * 16];
        const int rl = wv >> 1;
        const int jbase = (wv & 1) * 4;
        #pragma unroll
        for (int jj = 0; jj < 4; ++jj) {
            const int jg = jbase + jj;
            f32x4 d = (f32x4){0.f, 0.f, 0.f, 0.f};
            #pragma unroll
            for (int ks = 0; ks < 3; ++ks) {
                int o = rl * 4352 + (jg * 256 + (lane & 15) * 16 + ks * 32 + (lane >> 4) * 8) * 2;
                o ^= ((o >> 7) & 7) << 4;     // SWL
                short8 bfrag = *(const short8*)&sm[OKL + o];
                d = __builtin_amdgcn_mfma_f32_16x16x32_bf16(afr[ks], bfrag, d, 0, 0, 0);
            }
            unsigned pk0 = ((unsigned)f2bf(d[0])) | (((unsigned)f2bf(d[1])) << 16);
            unsigned pk1 = ((unsigned)f2bf(d[2])) | (((unsigned)f2bf(d[3])) << 16);
            int o2 = rl * 4096 + jg * 512 + (lane & 15) * 32 + (lane >> 4) * 8;
            o2 ^= ((o2 >> 9) & 7) << 4;       // SWK
            *(u32x2*)&sm[OKK + o2] = (u32x2){pk0, pk1};
        }
    }
    __syncthreads();   // B4

    {
        const int mt = wv;
        short8 par = *(const short8*)&sm[OPR + (mt * 16 + (lane & 15)) * 64 + (lane >> 4) * 16];
        short8 pai = *(const short8*)&sm[OPI + (mt * 16 + (lane & 15)) * 64 + (lane >> 4) * 16];
        float w32r[4], w32i[4];
        #pragma unroll
        for (int rg = 0; rg < 4; ++rg) {
            int n = mt * 16 + (lane >> 4) * 4 + rg;
            float2 ww = *(const float2*)&sm[OW32 + n * 8];
            w32r[rg] = ww.x;
            w32i[rg] = ww.y;
        }
        f32x4 cr = (f32x4){0.f, 0.f, 0.f, 0.f};
        f32x4 ci_ = (f32x4){0.f, 0.f, 0.f, 0.f};
        const int colb = (lane & 15) >> 3;
        const int colr = lane & 7;
        #pragma unroll
        for (int g2 = 0; g2 < 8; ++g2) {
            int o = colb * 4096 + colr * 512 + g2 * 64 + (lane >> 4) * 16;
            o ^= ((o >> 9) & 7) << 4;         // SWK
            short8 kf = *(const short8*)&sm[OKK + o];
            f32x4 sre = __builtin_amdgcn_mfma_f32_16x16x32_bf16(par, kf, (f32x4){0.f,0.f,0.f,0.f}, 0, 0, 0);
            f32x4 sim = __builtin_amdgcn_mfma_f32_16x16x32_bf16(pai, kf, (f32x4){0.f,0.f,0.f,0.f}, 0, 0, 0);
            #pragma unroll
            for (int rg = 0; rg < 4; ++rg) {
                float wr = w32r[rg], wi = w32i[rg];
                float ncr = fmaf(cr[rg], wr, fmaf(-ci_[rg], wi, sre[rg]));
                float nci = fmaf(cr[rg], wi, fmaf(ci_[rg], wr, sim[rg]));
                cr[rg] = ncr;
                ci_[rg] = nci;
            }
        }
        __syncthreads();   // B5
        #pragma unroll
        for (int rg = 0; rg < 4; ++rg) {
            int n = mt * 16 + (lane >> 4) * 4 + rg;
            int c = lane & 15;
            ((float*)&sm[OKK])[n * 17 + c] = cr[rg];
            ((float*)&sm[OKK])[1088 + n * 17 + c] = ci_[rg];
        }
    }
    __syncthreads();   // B6

    if (t < 128) {
        const int n = t & 63, bl = t >> 6;
        const int b = bg * 2 + bl;
        float Are, Aim, lre, lim;
        get_disc(log_dt, log_A_real, A_imag, h, n, Are, Aim, lre, lim);
        float er = expf(lre), sn, cs;
        sincosf(lim, &sn, &cs);
        float wr = er * cs, wi = er * sn;
        float2 w32v = *(const float2*)&sm[OW32 + n * 8];
        float ar = w32v.x, ai = w32v.y;
        #pragma unroll
        for (int s = 0; s < 3; ++s) {
            float nr = ar * ar - ai * ai;
            ai = 2.f * ar * ai;
            ar = nr;
        }
        float den = Are * Are + Aim * Aim;
        float wm1r = wr - 1.f, wm1i = wi;
        float tr_ = (wm1r * Are + wm1i * Aim) / den;
        float ti_ = (wm1i * Are - wm1r * Aim) / den;
        float br = B_re[h * 64 + n], bi = B_im[h * 64 + n];
        float dBr = br * tr_ - bi * ti_;
        float dBi = br * ti_ + bi * tr_;
        const float* cre = (const float*)&sm[OKK] + n * 17 + bl * 8;
        const float* cim = (const float*)&sm[OKK] + 1088 + n * 17 + bl * 8;
        float sr = 0.f, si_ = 0.f;
        #pragma unroll
        for (int r = 0; r < 8; ++r) {
            float nsr = fmaf(ar, sr, fmaf(-ai, si_, cre[r]));
            float nsi = fmaf(ar, si_, fmaf(ai, sr, cim[r]));
            sr = nsr; si_ = nsi;
            out[(((size_t)b * NREC + r) * DM + h) * 64 + n] = dBr * sr - dBi * si_;
        }
    }
}

extern "C" void kernel_launch(void* const* d_in, const int* in_sizes, int n_in,
                              void* d_out, int out_size, void* d_ws, size_t ws_size,
                              hipStream_t stream)
{
    const float* u       = (const float*)d_in[0];
    const float* W       = (const float*)d_in[1];
    const float* bias    = (const float*)d_in[2];
    const float* shift_B = (const float*)d_in[3];
    const float* shift_C = (const float*)d_in[4];
    const float* ssm_k_D = (const float*)d_in[5];
    const float* log_dt  = (const float*)d_in[6];
    const float* log_Ar  = (const float*)d_in[7];
    const float* A_imag  = (const float*)d_in[8];
    const float* B_re    = (const float*)d_in[9];
    const float* B_im    = (const float*)d_in[10];
    float* out = (float*)d_out;

    const int n_u = 8 * L_SEQ * DM;     // 16M elems
    const int n_w = DM * DM;            // 1M elems
    unsigned short* ub   = (unsigned short*)d_ws;            // [0, 32MB)
    unsigned short* klin = ub + (size_t)n_u;                 // [32MB, 64MB)
    unsigned short* Wb   = klin + (size_t)n_u;               // [64MB, 66MB)

    const bool prew = ws_size >= (size_t)66 * 1024 * 1024;

    if (prew) {
        cvt2_bf16<<<(n_u + n_w) / (256 * 8), 256, 0, stream>>>(u, ub, n_u, W, Wb, n_w);
        gemm_klin8<<<dim3(256), 512, 0, stream>>>(Wb, ub, bias, klin);
    } else {
        cvt2_bf16<<<n_u / (256 * 8), 256, 0, stream>>>(u, ub, n_u, W, Wb, 0);
        gemm_klin_fb<<<dim3(1024), 256, 0, stream>>>(W, ub, bias, klin);
    }

    expand<<<dim3(DM, 4), 256, 0, stream>>>(klin, shift_B, shift_C, ssm_k_D, log_dt,
                                            log_Ar, A_imag, B_re, B_im, out);
}

// Round 8
// 78.161 us; speedup vs baseline: 8.5933x; 1.0476x over previous
//
#include <hip/hip_runtime.h>
#include <cstddef>
#include <cstdint>

#define L_SEQ 2048
#define DM    1024
#define NREC  8

typedef __attribute__((ext_vector_type(8))) short short8;
typedef __attribute__((ext_vector_type(4))) float f32x4;
typedef __attribute__((ext_vector_type(2))) unsigned int u32x2;

__device__ inline unsigned short f2bf(float f) {
    unsigned u = __float_as_uint(f);
    unsigned r = (u + 0x7FFFu + ((u >> 16) & 1u)) >> 16;
    return (unsigned short)r;
}
__device__ inline float bf2f(unsigned short s) {
    return __uint_as_float(((unsigned)s) << 16);
}
__device__ inline void gload_lds16(const void* g, void* l) {
    __builtin_amdgcn_global_load_lds(
        (const __attribute__((address_space(1))) void*)g,
        (__attribute__((address_space(3))) void*)l, 16, 0, 0);
}
__device__ inline short8 pack8(f32x4 x, f32x4 y) {
    short8 c;
    c[0] = (short)f2bf(x[0]); c[1] = (short)f2bf(x[1]);
    c[2] = (short)f2bf(x[2]); c[3] = (short)f2bf(x[3]);
    c[4] = (short)f2bf(y[0]); c[5] = (short)f2bf(y[1]);
    c[6] = (short)f2bf(y[2]); c[7] = (short)f2bf(y[3]);
    return c;
}

// ============ fused-cvt 256x256 GEMM: klin[b][h][l] = W[h][:].u[b][l][:] + bias
// 8 waves (2M x 4N), BK=32, 2-deep LDS double-buffer (64 KB), reg-staged:
//   top of tile t: issue 8 f32x4 global loads for tile t+1 (distance-1, ~1200cyc slack)
//   compute tile t from buf[cur] (2 MFMA clusters, setprio)
//   then: [compiler vmcnt wait] cvt f32->bf16, 4x ds_write_b128 -> buf[cur^1]
//   __syncthreads (vmcnt already drained by the cvt's own wait -> no extra cost)
// LDS swizzle (proven 0-conflict r6/r7): pair p=row>>1 holds 8 granules (128B);
// logical g=(row&1)*4+slot; phys = g ^ (p&7). ds_write side applies the same
// involution; fragment read foff identical to r6/r7.
__global__ __launch_bounds__(512, 2) void gemm_fused(
    const float* __restrict__ Wf, const float* __restrict__ uf,
    const float* __restrict__ bias, unsigned short* __restrict__ klin)
{
    __shared__ unsigned short As[2][256 * 32];   // 2 x 16 KB
    __shared__ unsigned short Bs[2][256 * 32];   // 2 x 16 KB

    // XCD-contiguous: XCD x gets wg in [32x,32x+32) = one whole batch.
    int wg = (int)blockIdx.x;
    wg = (wg & 7) * 32 + (wg >> 3);
    const int b  = wg >> 5;
    const int l0 = ((wg >> 2) & 7) * 256;
    const int h0 = (wg & 3) * 256;
    const int tid = (int)threadIdx.x;
    const int lane = tid & 63, wv = tid >> 6;

    // staging geometry: thread covers rows sr0=tid>>2 and sr0+128, k-slot tid&3
    const int sr0  = tid >> 2;        // 0..127
    const int slot = tid & 3;
    const int sr1  = sr0 + 128;
    const float* gA0 = Wf + (size_t)(h0 + sr0) * DM + slot * 8;
    const float* gA1 = Wf + (size_t)(h0 + sr1) * DM + slot * 8;
    const float* gB0 = uf + ((size_t)b * L_SEQ + l0 + sr0) * DM + slot * 8;
    const float* gB1 = uf + ((size_t)b * L_SEQ + l0 + sr1) * DM + slot * 8;
    const int w0off = (sr0 >> 1) * 128 + ((((sr0 & 1) << 2) + slot) ^ ((sr0 >> 1) & 7)) * 16;
    const int w1off = (sr1 >> 1) * 128 + ((((sr1 & 1) << 2) + slot) ^ ((sr1 >> 1) & 7)) * 16;

    const int wm = wv >> 2, wn = wv & 3;
    const int lr = lane & 15, lk = lane >> 4;
    const int foff = (lr >> 1) * 128 + ((((lr & 1) << 2) + lk) ^ (lr >> 1)) * 16;

    f32x4 acc[8][4];
    #pragma unroll
    for (int mf = 0; mf < 8; ++mf)
        #pragma unroll
        for (int nf = 0; nf < 4; ++nf) acc[mf][nf] = (f32x4){0.f, 0.f, 0.f, 0.f};

    // prologue: stage tile 0
    {
        f32x4 a0 = *(const f32x4*)(gA0), a1 = *(const f32x4*)(gA0 + 4);
        f32x4 a2 = *(const f32x4*)(gA1), a3 = *(const f32x4*)(gA1 + 4);
        f32x4 b0 = *(const f32x4*)(gB0), b1 = *(const f32x4*)(gB0 + 4);
        f32x4 b2 = *(const f32x4*)(gB1), b3 = *(const f32x4*)(gB1 + 4);
        *(short8*)((char*)&As[0][0] + w0off) = pack8(a0, a1);
        *(short8*)((char*)&As[0][0] + w1off) = pack8(a2, a3);
        *(short8*)((char*)&Bs[0][0] + w0off) = pack8(b0, b1);
        *(short8*)((char*)&Bs[0][0] + w1off) = pack8(b2, b3);
    }
    __syncthreads();

    #pragma unroll 1
    for (int t = 0; t < 32; ++t) {
        const int cur = t & 1;
        const char* Ab = (const char*)&As[cur][0];
        const char* Bb = (const char*)&Bs[cur][0];
        f32x4 a0, a1, a2, a3, b0, b1, b2, b3;
        if (t < 31) {   // issue next-tile loads early (T14 split)
            const int ko = (t + 1) * 32;
            a0 = *(const f32x4*)(gA0 + ko); a1 = *(const f32x4*)(gA0 + ko + 4);
            a2 = *(const f32x4*)(gA1 + ko); a3 = *(const f32x4*)(gA1 + ko + 4);
            b0 = *(const f32x4*)(gB0 + ko); b1 = *(const f32x4*)(gB0 + ko + 4);
            b2 = *(const f32x4*)(gB1 + ko); b3 = *(const f32x4*)(gB1 + ko + 4);
        }
        short8 af[4], bfr[4];
        // ---- phase 0: B frags + A mf0-3, 16 MFMA ----
        #pragma unroll
        for (int nf = 0; nf < 4; ++nf)
            bfr[nf] = *(const short8*)(Bb + (wn * 64 + nf * 16) * 64 + foff);
        #pragma unroll
        for (int mf = 0; mf < 4; ++mf)
            af[mf] = *(const short8*)(Ab + (wm * 128 + mf * 16) * 64 + foff);
        __builtin_amdgcn_s_setprio(1);
        #pragma unroll
        for (int mf = 0; mf < 4; ++mf)
            #pragma unroll
            for (int nf = 0; nf < 4; ++nf)
                acc[mf][nf] = __builtin_amdgcn_mfma_f32_16x16x32_bf16(af[mf], bfr[nf], acc[mf][nf], 0, 0, 0);
        __builtin_amdgcn_s_setprio(0);
        // ---- phase 1: A mf4-7 (reuse B frags), 16 MFMA ----
        #pragma unroll
        for (int mf = 0; mf < 4; ++mf)
            af[mf] = *(const short8*)(Ab + (wm * 128 + (mf + 4) * 16) * 64 + foff);
        __builtin_amdgcn_s_setprio(1);
        #pragma unroll
        for (int mf = 0; mf < 4; ++mf)
            #pragma unroll
            for (int nf = 0; nf < 4; ++nf)
                acc[mf + 4][nf] = __builtin_amdgcn_mfma_f32_16x16x32_bf16(af[mf], bfr[nf], acc[mf + 4][nf], 0, 0, 0);
        __builtin_amdgcn_s_setprio(0);
        __builtin_amdgcn_sched_barrier(0);   // keep cvt (and its vmcnt wait) after MFMAs
        // ---- write-late: cvt + swizzled ds_write into the other buffer ----
        if (t < 31) {
            char* An = (char*)&As[cur ^ 1][0];
            char* Bn = (char*)&Bs[cur ^ 1][0];
            *(short8*)(An + w0off) = pack8(a0, a1);
            *(short8*)(An + w1off) = pack8(a2, a3);
            *(short8*)(Bn + w0off) = pack8(b0, b1);
            *(short8*)(Bn + w1off) = pack8(b2, b3);
            __syncthreads();
        }
    }

    // epilogue: D row=(lane>>4)*4+reg (h), col=lane&15 (l)
    #pragma unroll
    for (int mf = 0; mf < 8; ++mf) {
        const int h = h0 + wm * 128 + mf * 16 + lk * 4;
        #pragma unroll
        for (int nf = 0; nf < 4; ++nf) {
            const int l = l0 + wn * 64 + nf * 16 + lr;
            #pragma unroll
            for (int r = 0; r < 4; ++r) {
                float v = acc[mf][nf][r] + bias[h + r];
                klin[((size_t)b * DM + h + r) * L_SEQ + l] = f2bf(v);
            }
        }
    }
}

// ---------------- expand: one block per (h, b-pair); 29.7KB LDS (unchanged) ----
__device__ inline void get_disc(const float* __restrict__ log_dt,
                                const float* __restrict__ lar,
                                const float* __restrict__ aim, int h, int n,
                                float& Are, float& Aim, float& lre, float& lim)
{
    float dtv = expf(log_dt[h]);
    Are = -expf(lar[h * 64 + n]);
    Aim = aim[h * 64 + n];
    lre = dtv * Are;
    lim = dtv * Aim;
}

__global__ __launch_bounds__(256, 5) void expand(
    const unsigned short* __restrict__ klin,
    const float* __restrict__ shift_B, const float* __restrict__ shift_C,
    const float* __restrict__ ssm_k_D, const float* __restrict__ log_dt,
    const float* __restrict__ log_A_real, const float* __restrict__ A_imag,
    const float* __restrict__ B_re, const float* __restrict__ B_im,
    float* __restrict__ out)
{
    __shared__ __align__(16) char sm[29696];
    constexpr int OKL = 0;
    constexpr int OKK = 8704;
    constexpr int OAF = 16896;
    constexpr int OPR = 20224;
    constexpr int OPI = 24320;
    constexpr int OF  = 28416;
    constexpr int OBS = 28672;
    constexpr int OCS = 28928;
    constexpr int OW32 = 29184;

    const int h  = blockIdx.x;
    const int bg = blockIdx.y;
    const int t = threadIdx.x;
    const int lane = t & 63, wv = t >> 6;

    if (t < 32) {
        int rl = t >> 4, reg = (t >> 3) & 1, idx = t & 7;
        *(f32x4*)&sm[OKL + rl * 4352 + reg * 4224 + idx * 16] = (f32x4){0.f, 0.f, 0.f, 0.f};
    }
    {
        const int rl = wv >> 1, hf = wv & 1;
        const int b = bg * 2 + rl;
        const char* krow = (const char*)(klin + ((size_t)b * DM + h) * L_SEQ);
        const int s = (2 * rl + 1 + (lane >> 3)) & 7;
        const int so = hf * 2048 + (lane >> 3) * 128 + ((lane ^ s) & 7) * 16;
        gload_lds16(krow + so,        &sm[OKL + rl * 4352 + 128 + hf * 2048]);
        gload_lds16(krow + so + 1024, &sm[OKL + rl * 4352 + 128 + hf * 2048 + 1024]);
    }
    if (t < 64) {
        ((float*)&sm[OBS])[t] = shift_B[h * 64 + t];
        ((float*)&sm[OCS])[t] = shift_C[h * 64 + t];
        float Are, Aim, lre, lim;
        get_disc(log_dt, log_A_real, A_imag, h, t, Are, Aim, lre, lim);
        float er = expf(32.f * lre);
        float sn, cs; sincosf(32.f * lim, &sn, &cs);
        ((float*)&sm[OW32])[t * 2]     = er * cs;
        ((float*)&sm[OW32])[t * 2 + 1] = er * sn;
    }
    {
        int n = t >> 2, s4 = t & 3;
        float Are, Aim, lre, lim;
        get_disc(log_dt, log_A_real, A_imag, h, n, Are, Aim, lre, lim);
        float erw = expf(lre), snw, csw;
        sincosf(lim, &snw, &csw);
        float wr = erw * csw, wi = erw * snw;
        float e0 = (float)(24 - 8 * s4);
        float mag = expf(e0 * lre);
        float sn0, cs0; sincosf(e0 * lim, &sn0, &cs0);
        float pr = mag * cs0, pi = mag * sn0;
        float vr[8], vi[8];
        vr[7] = pr; vi[7] = pi;
        #pragma unroll
        for (int k = 6; k >= 0; --k) {
            float nr = pr * wr - pi * wi;
            pi = fmaf(pr, wi, pi * wr);
            pr = nr;
            vr[k] = pr; vi[k] = pi;
        }
        short8 re8, im8;
        #pragma unroll
        for (int e = 0; e < 8; ++e) {
            re8[e] = (short)f2bf(vr[e]);
            im8[e] = (short)f2bf(vi[e]);
        }
        *(short8*)&sm[OPR + t * 16] = re8;
        *(short8*)&sm[OPI + t * 16] = im8;
    }
    __syncthreads();   // B1

    if (t < 64) {
        const float* Bp = (const float*)&sm[OBS];
        const float* Cp = (const float*)&sm[OCS];
        float f = (t == 0) ? ssm_k_D[h] : 0.f;
        #pragma unroll 8
        for (int j = 0; j < 64; ++j) {
            float cv = Cp[(j + t) & 63];
            f = fmaf((j + t < 64) ? cv : 0.f, Bp[j], f);
        }
        ((float*)&sm[OF])[t] = f;
    }
    __syncthreads();   // B2

    {
        int i = t >> 4, ks = t & 15;
        if (ks < 12) {
            const float* Fp = (const float*)&sm[OF];
            short8 row;
            #pragma unroll
            for (int e = 0; e < 8; ++e) {
                int k = ks * 8 + e;
                int m = 64 + i - k;
                float v = (m >= 0 && m < 64) ? Fp[m] : 0.f;
                row[e] = (short)f2bf(v);
            }
            *(short8*)&sm[OAF + i * 208 + ks * 16] = row;
        }
    }
    __syncthreads();   // B3

    {
        short8 afr[3];
        #pragma unroll
        for (int ks = 0; ks < 3; ++ks)
            afr[ks] = *(const short8*)&sm[OAF + (lane & 15) * 208 + ks * 64 + (lane >> 4) * 16];
        const int rl = wv >> 1;
        const int jbase = (wv & 1) * 4;
        #pragma unroll
        for (int jj = 0; jj < 4; ++jj) {
            const int jg = jbase + jj;
            f32x4 d = (f32x4){0.f, 0.f, 0.f, 0.f};
            #pragma unroll
            for (int ks = 0; ks < 3; ++ks) {
                int o = rl * 4352 + (jg * 256 + (lane & 15) * 16 + ks * 32 + (lane >> 4) * 8) * 2;
                o ^= ((o >> 7) & 7) << 4;     // SWL
                short8 bfrag = *(const short8*)&sm[OKL + o];
                d = __builtin_amdgcn_mfma_f32_16x16x32_bf16(afr[ks], bfrag, d, 0, 0, 0);
            }
            unsigned pk0 = ((unsigned)f2bf(d[0])) | (((unsigned)f2bf(d[1])) << 16);
            unsigned pk1 = ((unsigned)f2bf(d[2])) | (((unsigned)f2bf(d[3])) << 16);
            int o2 = rl * 4096 + jg * 512 + (lane & 15) * 32 + (lane >> 4) * 8;
            o2 ^= ((o2 >> 9) & 7) << 4;       // SWK
            *(u32x2*)&sm[OKK + o2] = (u32x2){pk0, pk1};
        }
    }
    __syncthreads();   // B4

    {
        const int mt = wv;
        short8 par = *(const short8*)&sm[OPR + (mt * 16 + (lane & 15)) * 64 + (lane >> 4) * 16];
        short8 pai = *(const short8*)&sm[OPI + (mt * 16 + (lane & 15)) * 64 + (lane >> 4) * 16];
        float w32r[4], w32i[4];
        #pragma unroll
        for (int rg = 0; rg < 4; ++rg) {
            int n = mt * 16 + (lane >> 4) * 4 + rg;
            float2 ww = *(const float2*)&sm[OW32 + n * 8];
            w32r[rg] = ww.x;
            w32i[rg] = ww.y;
        }
        f32x4 cr = (f32x4){0.f, 0.f, 0.f, 0.f};
        f32x4 ci_ = (f32x4){0.f, 0.f, 0.f, 0.f};
        const int colb = (lane & 15) >> 3;
        const int colr = lane & 7;
        #pragma unroll
        for (int g2 = 0; g2 < 8; ++g2) {
            int o = colb * 4096 + colr * 512 + g2 * 64 + (lane >> 4) * 16;
            o ^= ((o >> 9) & 7) << 4;         // SWK
            short8 kf = *(const short8*)&sm[OKK + o];
            f32x4 sre = __builtin_amdgcn_mfma_f32_16x16x32_bf16(par, kf, (f32x4){0.f,0.f,0.f,0.f}, 0, 0, 0);
            f32x4 sim = __builtin_amdgcn_mfma_f32_16x16x32_bf16(pai, kf, (f32x4){0.f,0.f,0.f,0.f}, 0, 0, 0);
            #pragma unroll
            for (int rg = 0; rg < 4; ++rg) {
                float wr = w32r[rg], wi = w32i[rg];
                float ncr = fmaf(cr[rg], wr, fmaf(-ci_[rg], wi, sre[rg]));
                float nci = fmaf(cr[rg], wi, fmaf(ci_[rg], wr, sim[rg]));
                cr[rg] = ncr;
                ci_[rg] = nci;
            }
        }
        __syncthreads();   // B5
        #pragma unroll
        for (int rg = 0; rg < 4; ++rg) {
            int n = mt * 16 + (lane >> 4) * 4 + rg;
            int c = lane & 15;
            ((float*)&sm[OKK])[n * 17 + c] = cr[rg];
            ((float*)&sm[OKK])[1088 + n * 17 + c] = ci_[rg];
        }
    }
    __syncthreads();   // B6

    if (t < 128) {
        const int n = t & 63, bl = t >> 6;
        const int b = bg * 2 + bl;
        float Are, Aim, lre, lim;
        get_disc(log_dt, log_A_real, A_imag, h, n, Are, Aim, lre, lim);
        float er = expf(lre), sn, cs;
        sincosf(lim, &sn, &cs);
        float wr = er * cs, wi = er * sn;
        float2 w32v = *(const float2*)&sm[OW32 + n * 8];
        float ar = w32v.x, ai = w32v.y;
        #pragma unroll
        for (int s = 0; s < 3; ++s) {
            float nr = ar * ar - ai * ai;
            ai = 2.f * ar * ai;
            ar = nr;
        }
        float den = Are * Are + Aim * Aim;
        float wm1r = wr - 1.f, wm1i = wi;
        float tr_ = (wm1r * Are + wm1i * Aim) / den;
        float ti_ = (wm1i * Are - wm1r * Aim) / den;
        float br = B_re[h * 64 + n], bi = B_im[h * 64 + n];
        float dBr = br * tr_ - bi * ti_;
        float dBi = br * ti_ + bi * tr_;
        const float* cre = (const float*)&sm[OKK] + n * 17 + bl * 8;
        const float* cim = (const float*)&sm[OKK] + 1088 + n * 17 + bl * 8;
        float sr = 0.f, si_ = 0.f;
        #pragma unroll
        for (int r = 0; r < 8; ++r) {
            float nsr = fmaf(ar, sr, fmaf(-ai, si_, cre[r]));
            float nsi = fmaf(ar, si_, fmaf(ai, sr, cim[r]));
            sr = nsr; si_ = nsi;
            out[(((size_t)b * NREC + r) * DM + h) * 64 + n] = dBr * sr - dBi * si_;
        }
    }
}

extern "C" void kernel_launch(void* const* d_in, const int* in_sizes, int n_in,
                              void* d_out, int out_size, void* d_ws, size_t ws_size,
                              hipStream_t stream)
{
    const float* u       = (const float*)d_in[0];
    const float* W       = (const float*)d_in[1];
    const float* bias    = (const float*)d_in[2];
    const float* shift_B = (const float*)d_in[3];
    const float* shift_C = (const float*)d_in[4];
    const float* ssm_k_D = (const float*)d_in[5];
    const float* log_dt  = (const float*)d_in[6];
    const float* log_Ar  = (const float*)d_in[7];
    const float* A_imag  = (const float*)d_in[8];
    const float* B_re    = (const float*)d_in[9];
    const float* B_im    = (const float*)d_in[10];
    float* out = (float*)d_out;

    unsigned short* klin = (unsigned short*)d_ws;   // 32 MB

    gemm_fused<<<dim3(256), 512, 0, stream>>>(W, u, bias, klin);

    expand<<<dim3(DM, 4), 256, 0, stream>>>(klin, shift_B, shift_C, ssm_k_D, log_dt,
                                            log_Ar, A_imag, B_re, B_im, out);
}